// Round 6
// baseline (656.206 us; speedup 1.0000x reference)
//
#include <hip/hip_runtime.h>
#include <hip/hip_bf16.h>

typedef __attribute__((ext_vector_type(4))) float f32x4;
typedef __attribute__((ext_vector_type(8))) short s16x8;
typedef __attribute__((ext_vector_type(4))) unsigned short u16x4;

#define B_      32
#define S_      128
#define SEQ     129
#define IN_DIM  1024
#define HD      1024
#define NHEAD   8
#define DH      128
#define OUT_DIM 256
#define KC      10
#define DFF     2048
#define MROWS   (B_*SEQ)     // 4128
#define MPAD    4352         // 17 * 256 (covers 33*128 = 4224 too)
#define NCAND   (B_*S_*KC)   // 40960 = 320*128

__device__ __forceinline__ short f2bf(float f) {
  unsigned u = __builtin_bit_cast(unsigned, f);
  u += 0x7FFFu + ((u >> 16) & 1u);   // RNE to bf16
  return (short)(u >> 16);
}
__device__ __forceinline__ float bf2f(short s) {
  return __builtin_bit_cast(float, ((unsigned)(unsigned short)s) << 16);
}
__device__ __forceinline__ void gload16(const short* g, short* l) {
  __builtin_amdgcn_global_load_lds(
      (const __attribute__((address_space(1))) unsigned*)g,
      (__attribute__((address_space(3))) unsigned*)l, 16, 0, 0);
}

// ---------------- ALL weight transposes fused: W[K][N] f32 -> Wt[N][K] bf16 --
__global__ __launch_bounds__(256) void transpose_all(
    const float* __restrict__ W_in,  const float* __restrict__ Wqkv,
    const float* __restrict__ Wo,    const float* __restrict__ W1,
    const float* __restrict__ W2,    const float* __restrict__ W_out,
    const float* __restrict__ dsW1,
    short* __restrict__ WinT,  short* __restrict__ WqkvT,
    short* __restrict__ WoT,   short* __restrict__ W1T,
    short* __restrict__ W2T,   short* __restrict__ WoutT,
    short* __restrict__ dsW1T) {
  const int b = blockIdx.x;
  const float* src; short* dst; int K, N, local;
  if (b < 1024)       { src = W_in;  dst = WinT;  K = 1024; N = 1024; local = b; }
  else if (b < 7168)  { int l = (b - 1024) / 3072; local = (b - 1024) % 3072;
                        src = Wqkv + (size_t)l * 1024 * 3072;
                        dst = WqkvT + (size_t)l * 3072 * 1024; K = 1024; N = 3072; }
  else if (b < 9216)  { int l = (b - 7168) / 1024; local = (b - 7168) % 1024;
                        src = Wo + (size_t)l * 1024 * 1024;
                        dst = WoT + (size_t)l * 1024 * 1024; K = 1024; N = 1024; }
  else if (b < 13312) { int l = (b - 9216) / 2048; local = (b - 9216) % 2048;
                        src = W1 + (size_t)l * 1024 * 2048;
                        dst = W1T + (size_t)l * 2048 * 1024; K = 1024; N = 2048; }
  else if (b < 17408) { int l = (b - 13312) / 2048; local = (b - 13312) % 2048;
                        src = W2 + (size_t)l * 2048 * 1024;
                        dst = W2T + (size_t)l * 1024 * 2048; K = 2048; N = 1024; }
  else if (b < 17664) { local = b - 17408; src = W_out; dst = WoutT; K = 1024; N = 256; }
  else                { local = b - 17664; src = dsW1;  dst = dsW1T; K = 256;  N = 256; }
  const int tilesX = N >> 5;
  const int n0 = (local % tilesX) << 5, k0 = (local / tilesX) << 5;

  __shared__ float tile[32][33];
  const int tx = threadIdx.x & 31, ty = threadIdx.x >> 5;  // 32 x 8
#pragma unroll
  for (int i = 0; i < 4; ++i)
    tile[ty + i * 8][tx] = src[(size_t)(k0 + ty + i * 8) * N + n0 + tx];
  __syncthreads();
#pragma unroll
  for (int i = 0; i < 4; ++i)
    dst[(size_t)(n0 + ty + i * 8) * K + k0 + tx] = f2bf(tile[tx][ty + i * 8]);
}

// ---------------- GEMM: C[M][N] = A[M][K](bf16) * Bt[N][K](bf16) + bias ------
// BM x 256 tile, 8 waves (2x4), BK=32, 2-phase LDS double-buffer via
// global_load_lds with pre-swizzled source. XCD-chunked (m204) + groupM order.
// EPI: 0 none, 1 relu, 2 fused ds-score (requires BM=128, N=256, gn=1:
//      cand_out[row*257] = relu(acc+bias) . w2 + b2; no C-matrix write).
// A rows [bm, bm+BM) must be readable (pad M). N%256==0, K%64==0.
template <int EPI, int BM, typename OutT>
__global__ __launch_bounds__(512) void gemm_bt(const short* __restrict__ A,
                                               const short* __restrict__ Bt,
                                               const float* __restrict__ bias,
                                               OutT* __restrict__ C,
                                               int M, int N, int K,
                                               int gm, int gn, int groupM,
                                               const float* __restrict__ w2,
                                               const float* __restrict__ b2) {
  constexpr int ABUF = BM * 32;          // shorts per A buffer
  constexpr int BBUF = 256 * 32;         // shorts per B buffer
  constexpr int AISS = BM / 128;         // gload16 issues per A stage
  constexpr int MR   = BM / 32;          // m-fragments per wave (wave tile BM/2 x 64)
  __shared__ alignas(16) short lds[2 * ABUF + 2 * BBUF + (EPI == 2 ? 256 : 0)];
  short* As0 = lds;
  short* As1 = lds + ABUF;
  short* Bs0 = lds + 2 * ABUF;
  short* Bs1 = lds + 2 * ABUF + BBUF;
  float* red = (float*)(lds + 2 * ABUF + 2 * BBUF);

  const int tid = threadIdx.x;
  const int lane = tid & 63, wave = tid >> 6;
  const int wr = wave >> 2, wc = wave & 3;          // 2x4 waves

  // --- XCD-chunked bijective remap (m204) + grouped tile order --------------
  const int nwg = gm * gn;
  const int orig = blockIdx.x;
  const int xcd = orig & 7, kk = orig >> 3;
  const int q = nwg >> 3, r = nwg & 7;
  const int wg = (xcd < r ? xcd * (q + 1) : r * (q + 1) + (xcd - r) * q) + kk;
  const int tpg = groupM * gn;
  const int grp = wg / tpg, rem = wg % tpg;
  const int g0 = grp * groupM;
  const int gsz = (groupM < gm - g0) ? groupM : (gm - g0);
  const int bm = (g0 + rem % gsz) * BM;
  const int bn = (rem / gsz) * 256;

  if (EPI == 2 && tid < BM) red[tid] = 0.f;

  // staging: pre-swizzled global source, linear LDS dest.
  // idx = i*512 + tid; row rr = idx>>2; lds 16B-slot ss = idx&3;
  // global 16B-slot gg = ss ^ ((rr>>1)&3)
  const short* pa[AISS];
  const short* pb[2];
#pragma unroll
  for (int i = 0; i < AISS; ++i) {
    const int idx = i * 512 + tid;
    const int rr = idx >> 2, ss = idx & 3, gg = ss ^ ((rr >> 1) & 3);
    pa[i] = A + (size_t)(bm + rr) * K + gg * 8;
  }
#pragma unroll
  for (int i = 0; i < 2; ++i) {
    const int idx = i * 512 + tid;
    const int rr = idx >> 2, ss = idx & 3, gg = ss ^ ((rr >> 1) & 3);
    pb[i] = Bt + (size_t)(bn + rr) * K + gg * 8;
  }

  auto stage = [&](short* aBuf, short* bBuf, int tile) {
    const int kofs = tile << 5;
#pragma unroll
    for (int i = 0; i < AISS; ++i)
      gload16(pa[i] + kofs, aBuf + i * 4096 + wave * 512);
#pragma unroll
    for (int i = 0; i < 2; ++i)
      gload16(pb[i] + kofs, bBuf + i * 4096 + wave * 512);
  };

  // fragment reads (swizzled): row rr, k-slot ks -> shorts rr*32 + ((ks^sx)<<3)
  const int lrow = lane & 15, ks = lane >> 4;
  const int sx = (lrow >> 1) & 3;
  const int koff = ((ks ^ sx) << 3);

  f32x4 acc[MR][4] = {};

  auto compute = [&](const short* as, const short* bs) {
    s16x8 af[MR], bfr[4];
#pragma unroll
    for (int m = 0; m < MR; ++m)
      af[m] = *(const s16x8*)&as[(wr * (BM / 2) + m * 16 + lrow) * 32 + koff];
#pragma unroll
    for (int n = 0; n < 4; ++n)
      bfr[n] = *(const s16x8*)&bs[(wc * 64 + n * 16 + lrow) * 32 + koff];
#pragma unroll
    for (int m = 0; m < MR; ++m)
#pragma unroll
      for (int n = 0; n < 4; ++n)
        asm("v_mfma_f32_16x16x32_bf16 %0, %1, %2, %0"
            : "+v"(acc[m][n]) : "v"(af[m]), "v"(bfr[n]));
  };

  const int NT = K >> 5;                 // even at all call sites
  stage(As0, Bs0, 0);
  __syncthreads();
  for (int t = 0; t < NT; t += 2) {
    stage(As1, Bs1, t + 1);              // prefetch overlaps compute below
    compute(As0, Bs0);
    __syncthreads();
    if (t + 2 < NT) stage(As0, Bs0, t + 2);
    compute(As1, Bs1);
    __syncthreads();
  }

  if constexpr (EPI == 2) {
    // fused ds-score: per row, sum over all 256 cols of relu(v + b1) * w2
    float w2v[4], bv[4];
#pragma unroll
    for (int n = 0; n < 4; ++n) {
      const int col = wc * 64 + n * 16 + lrow;
      w2v[n] = w2[col];
      bv[n] = bias[col];
    }
#pragma unroll
    for (int m = 0; m < MR; ++m) {
#pragma unroll
      for (int r2 = 0; r2 < 4; ++r2) {
        float part = 0.f;
#pragma unroll
        for (int n = 0; n < 4; ++n)
          part += fmaxf(acc[m][n][r2] + bv[n], 0.f) * w2v[n];
        part += __shfl_xor(part, 1);
        part += __shfl_xor(part, 2);
        part += __shfl_xor(part, 4);
        part += __shfl_xor(part, 8);
        if (lrow == 0)
          atomicAdd(&red[wr * (BM / 2) + m * 16 + ks * 4 + r2], part);
      }
    }
    __syncthreads();
    if (tid < BM)
      ((float*)C)[(size_t)(bm + tid) * 257] = red[tid] + b2[0];
    return;
  }

  const int lg4 = ks << 2;
#pragma unroll
  for (int n = 0; n < 4; ++n) {
    const int col = bn + wc * 64 + n * 16 + lrow;
    const float bvx = bias[col];
#pragma unroll
    for (int m = 0; m < MR; ++m) {
#pragma unroll
      for (int r2 = 0; r2 < 4; ++r2) {
        const int row = bm + wr * (BM / 2) + m * 16 + lg4 + r2;
        if (row < M) {
          float v = acc[m][n][r2] + bvx;
          if (EPI == 1) v = fmaxf(v, 0.f);
          if constexpr (__is_same(OutT, float)) {
            C[(size_t)row * N + col] = v;
          } else {
            C[(size_t)row * N + col] = f2bf(v);
          }
        }
      }
    }
  }
}

// ---------------- build h_in = concat([ctx, x], axis=1) -> bf16 --------------
__global__ __launch_bounds__(256) void build_hin(const float* __restrict__ x,
                                                 const float* __restrict__ ctx,
                                                 short* __restrict__ hin) {
  const int r = blockIdx.x;
  const int b = r / SEQ, t = r % SEQ;
  const float* src = (t == 0) ? (ctx + (size_t)b * IN_DIM)
                              : (x + ((size_t)b * S_ + (t - 1)) * IN_DIM);
  f32x4 v = *(const f32x4*)(src + threadIdx.x * 4);
  u16x4 o;
  o.x = (unsigned short)f2bf(v.x); o.y = (unsigned short)f2bf(v.y);
  o.z = (unsigned short)f2bf(v.z); o.w = (unsigned short)f2bf(v.w);
  *(u16x4*)(hin + (size_t)r * IN_DIM + threadIdx.x * 4) = o;
}

// ---------------- attention over batch axis (32) at each (pos t, head) ------
__global__ __launch_bounds__(128) void attention_kern(const short* __restrict__ qkv,
                                                      short* __restrict__ o) {
  __shared__ alignas(16) float qs[32][132], ksm[32][132], vs[32][132];
  __shared__ float ps[32][33];
  const int t = blockIdx.x, hd = blockIdx.y, tid = threadIdx.x;
  for (int i = tid; i < 32 * 16; i += 128) {   // 32 rows x 16 chunks of 8 bf16
    const int bb = i >> 4, d8 = (i & 15) << 3;
    const size_t base = (size_t)(bb * SEQ + t) * (3 * HD) + hd * DH + d8;
    s16x8 q8 = *(const s16x8*)(qkv + base);
    s16x8 k8 = *(const s16x8*)(qkv + base + HD);
    s16x8 v8 = *(const s16x8*)(qkv + base + 2 * HD);
#pragma unroll
    for (int j = 0; j < 8; ++j) {
      qs[bb][d8 + j] = bf2f(q8[j]);
      ksm[bb][d8 + j] = bf2f(k8[j]);
      vs[bb][d8 + j] = bf2f(v8[j]);
    }
  }
  __syncthreads();
  const float scale = 0.08838834764831845f;   // 1/sqrt(128)
  for (int idx = tid; idx < 1024; idx += 128) {
    const int i = idx >> 5, j = idx & 31;
    float s = 0.f;
#pragma unroll 8
    for (int d = 0; d < DH; ++d) s += qs[i][d] * ksm[j][d];
    ps[i][j] = s * scale;
  }
  __syncthreads();
  if (tid < 32) {
    float mx = -1e30f;
#pragma unroll
    for (int j = 0; j < 32; ++j) mx = fmaxf(mx, ps[tid][j]);
    float sum = 0.f;
#pragma unroll
    for (int j = 0; j < 32; ++j) { float e = __expf(ps[tid][j] - mx); ps[tid][j] = e; sum += e; }
    const float inv = 1.f / sum;
#pragma unroll
    for (int j = 0; j < 32; ++j) ps[tid][j] *= inv;
  }
  __syncthreads();
  for (int idx = tid; idx < 32 * DH; idx += 128) {
    const int i = idx >> 7, d = idx & 127;
    float s = 0.f;
#pragma unroll
    for (int j = 0; j < 32; ++j) s += ps[i][j] * vs[j][d];
    o[(size_t)(i * SEQ + t) * HD + hd * DH + d] = f2bf(s);
  }
}

// ---------------- y = LN(h + delta) * g + b  (bf16 in / bf16 out) -----------
__global__ __launch_bounds__(256) void add_ln(const short* __restrict__ hin,
                                              const short* __restrict__ delta,
                                              const float* __restrict__ g,
                                              const float* __restrict__ bb,
                                              short* __restrict__ hout) {
  const int r = blockIdx.x, tid = threadIdx.x;
  const u16x4 hv = *(const u16x4*)(hin + (size_t)r * HD + tid * 4);
  const u16x4 dv = *(const u16x4*)(delta + (size_t)r * HD + tid * 4);
  float s0 = bf2f((short)hv.x) + bf2f((short)dv.x);
  float s1 = bf2f((short)hv.y) + bf2f((short)dv.y);
  float s2 = bf2f((short)hv.z) + bf2f((short)dv.z);
  float s3 = bf2f((short)hv.w) + bf2f((short)dv.w);
  float ls = s0 + s1 + s2 + s3;
  float l2 = s0 * s0 + s1 * s1 + s2 * s2 + s3 * s3;
#pragma unroll
  for (int off = 32; off > 0; off >>= 1) {
    ls += __shfl_down(ls, off);
    l2 += __shfl_down(l2, off);
  }
  __shared__ float red[8];
  const int wave = tid >> 6, lane = tid & 63;
  if (lane == 0) { red[wave * 2] = ls; red[wave * 2 + 1] = l2; }
  __syncthreads();
  if (tid == 0) {
    float a = 0.f, b2 = 0.f;
    for (int w = 0; w < 4; ++w) { a += red[w * 2]; b2 += red[w * 2 + 1]; }
    red[0] = a; red[1] = b2;
  }
  __syncthreads();
  const float mean = red[0] * (1.f / HD);
  const float var  = red[1] * (1.f / HD) - mean * mean;
  const float inv  = rsqrtf(var + 1e-5f);
  const f32x4 gv = *(const f32x4*)(g + tid * 4);
  const f32x4 bv = *(const f32x4*)(bb + tid * 4);
  u16x4 y;
  y.x = (unsigned short)f2bf((s0 - mean) * inv * gv.x + bv.x);
  y.y = (unsigned short)f2bf((s1 - mean) * inv * gv.y + bv.y);
  y.z = (unsigned short)f2bf((s2 - mean) * inv * gv.z + bv.z);
  y.w = (unsigned short)f2bf((s3 - mean) * inv * gv.w + bv.w);
  *(u16x4*)(hout + (size_t)r * HD + tid * 4) = y;
}

// ---- pred write + gather cand + cand_out[..,1:] + dbuf = bf16(cand-pred) ----
__global__ __launch_bounds__(256) void gather_cand(const float* __restrict__ outb,
                                                   const int* __restrict__ indices,
                                                   const float* __restrict__ KB,
                                                   float* __restrict__ pred,
                                                   float* __restrict__ cand_out,
                                                   short* __restrict__ dbuf) {
  const int bs = blockIdx.x;
  const int b = bs >> 7, s = bs & 127;
  const int c = threadIdx.x;
  const float p = outb[((size_t)b * SEQ + s + 1) * OUT_DIM + c];
  pred[(size_t)bs * OUT_DIM + c] = p;
  const int* idxp = indices + (size_t)bs * KC;
  for (int k = 0; k < KC; ++k) {
    int idx = idxp[k];
    if (idx < 0) idx = 0;
    const float cv = KB[(size_t)idx * OUT_DIM + c];
    const size_t row = (size_t)bs * KC + k;
    cand_out[row * 257 + 1 + c] = cv;
    dbuf[row * OUT_DIM + c] = f2bf(cv - p);
  }
}

extern "C" void kernel_launch(void* const* d_in, const int* in_sizes, int n_in,
                              void* d_out, int out_size, void* d_ws, size_t ws_size,
                              hipStream_t stream) {
  const float* x      = (const float*)d_in[0];
  const float* ctx    = (const float*)d_in[1];
  const int*   indices= (const int*)d_in[2];
  const float* KB     = (const float*)d_in[3];
  const float* W_in   = (const float*)d_in[4];
  const float* b_in   = (const float*)d_in[5];
  const float* Wqkv   = (const float*)d_in[6];
  const float* bqkv   = (const float*)d_in[7];
  const float* Wo     = (const float*)d_in[8];
  const float* bo     = (const float*)d_in[9];
  const float* ln1_g  = (const float*)d_in[10];
  const float* ln1_b  = (const float*)d_in[11];
  const float* W1     = (const float*)d_in[12];
  const float* b1     = (const float*)d_in[13];
  const float* W2     = (const float*)d_in[14];
  const float* b2     = (const float*)d_in[15];
  const float* ln2_g  = (const float*)d_in[16];
  const float* ln2_b  = (const float*)d_in[17];
  const float* W_out  = (const float*)d_in[18];
  const float* b_out  = (const float*)d_in[19];
  const float* ds_W1  = (const float*)d_in[20];
  const float* ds_b1  = (const float*)d_in[21];
  const float* ds_W2  = (const float*)d_in[22];
  const float* ds_b2  = (const float*)d_in[23];
  // d_in[24..27] = cs_* : dead code in reference (del cs)

  char* p = (char*)d_ws;
  auto alloc = [&](size_t bytes) {
    char* q = p;
    p += (bytes + 255) & ~(size_t)255;
    return q;
  };
  short* h    = (short*)alloc((size_t)MPAD * HD * 2);
  short* tmp1 = (short*)alloc((size_t)MPAD * 3 * HD * 2);  // qkv / ff1
  short* tmp2 = (short*)alloc((size_t)MPAD * HD * 2);      // hin / attn-o
  short* tmp3 = (short*)alloc((size_t)MPAD * HD * 2);      // Wo out / ff2
  float* outb = (float*)alloc((size_t)MROWS * OUT_DIM * 4);
  short* dbuf = (short*)alloc((size_t)NCAND * OUT_DIM * 2);
  short* WinT  = (short*)alloc((size_t)HD * IN_DIM * 2);
  short* WqkvT = (short*)alloc((size_t)2 * 3 * HD * HD * 2);
  short* WoT   = (short*)alloc((size_t)2 * HD * HD * 2);
  short* W1T   = (short*)alloc((size_t)2 * DFF * HD * 2);
  short* W2T   = (short*)alloc((size_t)2 * HD * DFF * 2);
  short* WoutT = (short*)alloc((size_t)OUT_DIM * HD * 2);
  short* dsW1T = (short*)alloc((size_t)OUT_DIM * OUT_DIM * 2);

  // all weight transposes (f32 -> bf16, N x K) in ONE dispatch
  transpose_all<<<17728, 256, 0, stream>>>(W_in, Wqkv, Wo, W1, W2, W_out, ds_W1,
                                           WinT, WqkvT, WoT, W1T, W2T, WoutT, dsW1T);

  // forward
  build_hin<<<MROWS, 256, 0, stream>>>(x, ctx, tmp2);
  gemm_bt<1, 256, short><<<17 * 4, 512, 0, stream>>>(
      tmp2, WinT, b_in, h, MROWS, 1024, 1024, 17, 4, 4, nullptr, nullptr);

  for (int l = 0; l < 2; ++l) {
    gemm_bt<0, 256, short><<<17 * 12, 512, 0, stream>>>(
        h, WqkvT + (size_t)l * 3072 * 1024, bqkv + l * 3072, tmp1,
        MROWS, 3072, 1024, 17, 12, 4, nullptr, nullptr);
    attention_kern<<<dim3(SEQ, NHEAD), 128, 0, stream>>>(tmp1, tmp2);
    gemm_bt<0, 256, short><<<17 * 4, 512, 0, stream>>>(
        tmp2, WoT + (size_t)l * 1024 * 1024, bo + l * 1024, tmp3,
        MROWS, 1024, 1024, 17, 4, 4, nullptr, nullptr);
    add_ln<<<MROWS, 256, 0, stream>>>(h, tmp3, ln1_g + l * 1024, ln1_b + l * 1024, h);
    gemm_bt<1, 256, short><<<17 * 8, 512, 0, stream>>>(
        h, W1T + (size_t)l * 2048 * 1024, b1 + l * 2048, tmp1,
        MROWS, 2048, 1024, 17, 8, 4, nullptr, nullptr);
    gemm_bt<0, 256, short><<<17 * 4, 512, 0, stream>>>(
        tmp1, W2T + (size_t)l * 1024 * 2048, b2 + l * 1024, tmp3,
        MROWS, 1024, 2048, 17, 4, 4, nullptr, nullptr);
    add_ln<<<MROWS, 256, 0, stream>>>(h, tmp3, ln2_g + l * 1024, ln2_b + l * 1024, h);
  }

  gemm_bt<0, 128, float><<<33 * 1, 512, 0, stream>>>(
      h, WoutT, b_out, outb, MROWS, 256, 1024, 33, 1, 33, nullptr, nullptr);

  float* pred = (float*)d_out;
  float* cand_out = (float*)d_out + (size_t)B_ * S_ * OUT_DIM;
  gather_cand<<<4096, 256, 0, stream>>>(outb, indices, KB, pred, cand_out, dbuf);
  // ds GEMM with fused score epilogue: writes cand_out[row*257] directly
  gemm_bt<2, 128, float><<<320 * 1, 512, 0, stream>>>(
      dbuf, dsW1T, ds_b1, cand_out, NCAND, 256, 256, 320, 1, 320, ds_W2, ds_b2);
}

// Round 7
// 655.321 us; speedup vs baseline: 1.0014x; 1.0014x over previous
//
#include <hip/hip_runtime.h>
#include <hip/hip_bf16.h>

typedef __attribute__((ext_vector_type(4))) float f32x4;
typedef __attribute__((ext_vector_type(8))) short s16x8;
typedef __attribute__((ext_vector_type(4))) unsigned short u16x4;

#define B_      32
#define S_      128
#define SEQ     129
#define IN_DIM  1024
#define HD      1024
#define NHEAD   8
#define DH      128
#define OUT_DIM 256
#define KC      10
#define DFF     2048
#define MROWS   (B_*SEQ)     // 4128
#define MPAD    4352         // 17 * 256 (covers 33*128 = 4224 too)
#define NCAND   (B_*S_*KC)   // 40960 = 320*128

__device__ __forceinline__ short f2bf(float f) {
  unsigned u = __builtin_bit_cast(unsigned, f);
  u += 0x7FFFu + ((u >> 16) & 1u);   // RNE to bf16
  return (short)(u >> 16);
}
__device__ __forceinline__ float bf2f(short s) {
  return __builtin_bit_cast(float, ((unsigned)(unsigned short)s) << 16);
}
__device__ __forceinline__ void gload16(const short* g, short* l) {
  __builtin_amdgcn_global_load_lds(
      (const __attribute__((address_space(1))) unsigned*)g,
      (__attribute__((address_space(3))) unsigned*)l, 16, 0, 0);
}

// ---------------- ALL weight transposes fused: W[K][N] f32 -> Wt[N][K] bf16 --
__global__ __launch_bounds__(256) void transpose_all(
    const float* __restrict__ W_in,  const float* __restrict__ Wqkv,
    const float* __restrict__ Wo,    const float* __restrict__ W1,
    const float* __restrict__ W2,    const float* __restrict__ W_out,
    const float* __restrict__ dsW1,
    short* __restrict__ WinT,  short* __restrict__ WqkvT,
    short* __restrict__ WoT,   short* __restrict__ W1T,
    short* __restrict__ W2T,   short* __restrict__ WoutT,
    short* __restrict__ dsW1T) {
  const int b = blockIdx.x;
  const float* src; short* dst; int K, N, local;
  if (b < 1024)       { src = W_in;  dst = WinT;  K = 1024; N = 1024; local = b; }
  else if (b < 7168)  { int l = (b - 1024) / 3072; local = (b - 1024) % 3072;
                        src = Wqkv + (size_t)l * 1024 * 3072;
                        dst = WqkvT + (size_t)l * 3072 * 1024; K = 1024; N = 3072; }
  else if (b < 9216)  { int l = (b - 7168) / 1024; local = (b - 7168) % 1024;
                        src = Wo + (size_t)l * 1024 * 1024;
                        dst = WoT + (size_t)l * 1024 * 1024; K = 1024; N = 1024; }
  else if (b < 13312) { int l = (b - 9216) / 2048; local = (b - 9216) % 2048;
                        src = W1 + (size_t)l * 1024 * 2048;
                        dst = W1T + (size_t)l * 2048 * 1024; K = 1024; N = 2048; }
  else if (b < 17408) { int l = (b - 13312) / 2048; local = (b - 13312) % 2048;
                        src = W2 + (size_t)l * 2048 * 1024;
                        dst = W2T + (size_t)l * 1024 * 2048; K = 2048; N = 1024; }
  else if (b < 17664) { local = b - 17408; src = W_out; dst = WoutT; K = 1024; N = 256; }
  else                { local = b - 17664; src = dsW1;  dst = dsW1T; K = 256;  N = 256; }
  const int tilesX = N >> 5;
  const int n0 = (local % tilesX) << 5, k0 = (local / tilesX) << 5;

  __shared__ float tile[32][33];
  const int tx = threadIdx.x & 31, ty = threadIdx.x >> 5;  // 32 x 8
#pragma unroll
  for (int i = 0; i < 4; ++i)
    tile[ty + i * 8][tx] = src[(size_t)(k0 + ty + i * 8) * N + n0 + tx];
  __syncthreads();
#pragma unroll
  for (int i = 0; i < 4; ++i)
    dst[(size_t)(n0 + ty + i * 8) * K + k0 + tx] = f2bf(tile[tx][ty + i * 8]);
}

// ---------------- GEMM: C[M][N] = A[M][K](bf16) * Bt[N][K](bf16) + bias ------
// BM x 256 tile, 8 waves (2x4), BK=32, 2-phase LDS double-buffer via
// global_load_lds with pre-swizzled source. XCD-chunked (m204) + groupM order.
// EPI: 0 none, 1 relu, 2 fused ds-score (requires BM=128, N=256, gn=1:
//      cand_out[row*257] = relu(acc+bias) . w2 + b2; no C-matrix write).
// A rows [bm, bm+BM) must be readable (pad M). N%256==0, K%64==0.
template <int EPI, int BM, typename OutT>
__global__ __launch_bounds__(512) void gemm_bt(const short* __restrict__ A,
                                               const short* __restrict__ Bt,
                                               const float* __restrict__ bias,
                                               OutT* __restrict__ C,
                                               int M, int N, int K,
                                               int gm, int gn, int groupM,
                                               const float* __restrict__ w2,
                                               const float* __restrict__ b2) {
  constexpr int ABUF = BM * 32;          // shorts per A buffer
  constexpr int BBUF = 256 * 32;         // shorts per B buffer
  constexpr int AISS = BM / 128;         // gload16 issues per A stage
  constexpr int MR   = BM / 32;          // m-fragments per wave (wave tile BM/2 x 64)
  __shared__ alignas(16) short lds[2 * ABUF + 2 * BBUF + (EPI == 2 ? 256 : 0)];
  short* As0 = lds;
  short* As1 = lds + ABUF;
  short* Bs0 = lds + 2 * ABUF;
  short* Bs1 = lds + 2 * ABUF + BBUF;
  float* red = (float*)(lds + 2 * ABUF + 2 * BBUF);

  const int tid = threadIdx.x;
  const int lane = tid & 63, wave = tid >> 6;
  const int wr = wave >> 2, wc = wave & 3;          // 2x4 waves

  // --- XCD-chunked bijective remap (m204) + grouped tile order --------------
  const int nwg = gm * gn;
  const int orig = blockIdx.x;
  const int xcd = orig & 7, kk = orig >> 3;
  const int q = nwg >> 3, r = nwg & 7;
  const int wg = (xcd < r ? xcd * (q + 1) : r * (q + 1) + (xcd - r) * q) + kk;
  const int tpg = groupM * gn;
  const int grp = wg / tpg, rem = wg % tpg;
  const int g0 = grp * groupM;
  const int gsz = (groupM < gm - g0) ? groupM : (gm - g0);
  const int bm = (g0 + rem % gsz) * BM;
  const int bn = (rem / gsz) * 256;

  if (EPI == 2 && tid < BM) red[tid] = 0.f;

  // staging: pre-swizzled global source, linear LDS dest.
  // idx = i*512 + tid; row rr = idx>>2; lds 16B-slot ss = idx&3;
  // global 16B-slot gg = ss ^ ((rr>>1)&3)
  const short* pa[AISS];
  const short* pb[2];
#pragma unroll
  for (int i = 0; i < AISS; ++i) {
    const int idx = i * 512 + tid;
    const int rr = idx >> 2, ss = idx & 3, gg = ss ^ ((rr >> 1) & 3);
    pa[i] = A + (size_t)(bm + rr) * K + gg * 8;
  }
#pragma unroll
  for (int i = 0; i < 2; ++i) {
    const int idx = i * 512 + tid;
    const int rr = idx >> 2, ss = idx & 3, gg = ss ^ ((rr >> 1) & 3);
    pb[i] = Bt + (size_t)(bn + rr) * K + gg * 8;
  }

  auto stage = [&](short* aBuf, short* bBuf, int tile) {
    const int kofs = tile << 5;
#pragma unroll
    for (int i = 0; i < AISS; ++i)
      gload16(pa[i] + kofs, aBuf + i * 4096 + wave * 512);
#pragma unroll
    for (int i = 0; i < 2; ++i)
      gload16(pb[i] + kofs, bBuf + i * 4096 + wave * 512);
  };

  // fragment reads (swizzled): row rr, k-slot ks -> shorts rr*32 + ((ks^sx)<<3)
  const int lrow = lane & 15, ks = lane >> 4;
  const int sx = (lrow >> 1) & 3;
  const int koff = ((ks ^ sx) << 3);

  f32x4 acc[MR][4] = {};

  auto compute = [&](const short* as, const short* bs) {
    s16x8 af[MR], bfr[4];
#pragma unroll
    for (int m = 0; m < MR; ++m)
      af[m] = *(const s16x8*)&as[(wr * (BM / 2) + m * 16 + lrow) * 32 + koff];
#pragma unroll
    for (int n = 0; n < 4; ++n)
      bfr[n] = *(const s16x8*)&bs[(wc * 64 + n * 16 + lrow) * 32 + koff];
#pragma unroll
    for (int m = 0; m < MR; ++m)
#pragma unroll
      for (int n = 0; n < 4; ++n)
        asm("v_mfma_f32_16x16x32_bf16 %0, %1, %2, %0"
            : "+v"(acc[m][n]) : "v"(af[m]), "v"(bfr[n]));
  };

  const int NT = K >> 5;                 // even at all call sites
  stage(As0, Bs0, 0);
  __syncthreads();
  for (int t = 0; t < NT; t += 2) {
    stage(As1, Bs1, t + 1);              // prefetch overlaps compute below
    compute(As0, Bs0);
    __syncthreads();
    if (t + 2 < NT) stage(As0, Bs0, t + 2);
    compute(As1, Bs1);
    __syncthreads();
  }

  if constexpr (EPI == 2) {
    // fused ds-score: per row, sum over all 256 cols of relu(v + b1) * w2
    float w2v[4], bv[4];
#pragma unroll
    for (int n = 0; n < 4; ++n) {
      const int col = wc * 64 + n * 16 + lrow;
      w2v[n] = w2[col];
      bv[n] = bias[col];
    }
#pragma unroll
    for (int m = 0; m < MR; ++m) {
#pragma unroll
      for (int r2 = 0; r2 < 4; ++r2) {
        float part = 0.f;
#pragma unroll
        for (int n = 0; n < 4; ++n)
          part += fmaxf(acc[m][n][r2] + bv[n], 0.f) * w2v[n];
        part += __shfl_xor(part, 1);
        part += __shfl_xor(part, 2);
        part += __shfl_xor(part, 4);
        part += __shfl_xor(part, 8);
        if (lrow == 0)
          atomicAdd(&red[wr * (BM / 2) + m * 16 + ks * 4 + r2], part);
      }
    }
    __syncthreads();
    if (tid < BM)
      ((float*)C)[(size_t)(bm + tid) * 257] = red[tid] + b2[0];
    return;
  }

  const int lg4 = ks << 2;
#pragma unroll
  for (int n = 0; n < 4; ++n) {
    const int col = bn + wc * 64 + n * 16 + lrow;
    const float bvx = bias[col];
#pragma unroll
    for (int m = 0; m < MR; ++m) {
#pragma unroll
      for (int r2 = 0; r2 < 4; ++r2) {
        const int row = bm + wr * (BM / 2) + m * 16 + lg4 + r2;
        if (row < M) {
          float v = acc[m][n][r2] + bvx;
          if (EPI == 1) v = fmaxf(v, 0.f);
          if constexpr (__is_same(OutT, float)) {
            C[(size_t)row * N + col] = v;
          } else {
            C[(size_t)row * N + col] = f2bf(v);
          }
        }
      }
    }
  }
}

// ---------------- build h_in = concat([ctx, x], axis=1) -> bf16 --------------
__global__ __launch_bounds__(256) void build_hin(const float* __restrict__ x,
                                                 const float* __restrict__ ctx,
                                                 short* __restrict__ hin) {
  const int r = blockIdx.x;
  const int b = r / SEQ, t = r % SEQ;
  const float* src = (t == 0) ? (ctx + (size_t)b * IN_DIM)
                              : (x + ((size_t)b * S_ + (t - 1)) * IN_DIM);
  f32x4 v = *(const f32x4*)(src + threadIdx.x * 4);
  u16x4 o;
  o.x = (unsigned short)f2bf(v.x); o.y = (unsigned short)f2bf(v.y);
  o.z = (unsigned short)f2bf(v.z); o.w = (unsigned short)f2bf(v.w);
  *(u16x4*)(hin + (size_t)r * IN_DIM + threadIdx.x * 4) = o;
}

// ---------------- attention over batch axis (32) at each (pos t, head) ------
__global__ __launch_bounds__(128) void attention_kern(const short* __restrict__ qkv,
                                                      short* __restrict__ o) {
  __shared__ alignas(16) float qs[32][132], ksm[32][132], vs[32][132];
  __shared__ float ps[32][33];
  const int t = blockIdx.x, hd = blockIdx.y, tid = threadIdx.x;
  for (int i = tid; i < 32 * 16; i += 128) {   // 32 rows x 16 chunks of 8 bf16
    const int bb = i >> 4, d8 = (i & 15) << 3;
    const size_t base = (size_t)(bb * SEQ + t) * (3 * HD) + hd * DH + d8;
    s16x8 q8 = *(const s16x8*)(qkv + base);
    s16x8 k8 = *(const s16x8*)(qkv + base + HD);
    s16x8 v8 = *(const s16x8*)(qkv + base + 2 * HD);
#pragma unroll
    for (int j = 0; j < 8; ++j) {
      qs[bb][d8 + j] = bf2f(q8[j]);
      ksm[bb][d8 + j] = bf2f(k8[j]);
      vs[bb][d8 + j] = bf2f(v8[j]);
    }
  }
  __syncthreads();
  const float scale = 0.08838834764831845f;   // 1/sqrt(128)
  for (int idx = tid; idx < 1024; idx += 128) {
    const int i = idx >> 5, j = idx & 31;
    float s = 0.f;
#pragma unroll 8
    for (int d = 0; d < DH; ++d) s += qs[i][d] * ksm[j][d];
    ps[i][j] = s * scale;
  }
  __syncthreads();
  if (tid < 32) {
    float mx = -1e30f;
#pragma unroll
    for (int j = 0; j < 32; ++j) mx = fmaxf(mx, ps[tid][j]);
    float sum = 0.f;
#pragma unroll
    for (int j = 0; j < 32; ++j) { float e = __expf(ps[tid][j] - mx); ps[tid][j] = e; sum += e; }
    const float inv = 1.f / sum;
#pragma unroll
    for (int j = 0; j < 32; ++j) ps[tid][j] *= inv;
  }
  __syncthreads();
  for (int idx = tid; idx < 32 * DH; idx += 128) {
    const int i = idx >> 7, d = idx & 127;
    float s = 0.f;
#pragma unroll
    for (int j = 0; j < 32; ++j) s += ps[i][j] * vs[j][d];
    o[(size_t)(i * SEQ + t) * HD + hd * DH + d] = f2bf(s);
  }
}

// ---------------- y = LN(h + delta) * g + b  (bf16 in / bf16 out) -----------
__global__ __launch_bounds__(256) void add_ln(const short* __restrict__ hin,
                                              const short* __restrict__ delta,
                                              const float* __restrict__ g,
                                              const float* __restrict__ bb,
                                              short* __restrict__ hout) {
  const int r = blockIdx.x, tid = threadIdx.x;
  const u16x4 hv = *(const u16x4*)(hin + (size_t)r * HD + tid * 4);
  const u16x4 dv = *(const u16x4*)(delta + (size_t)r * HD + tid * 4);
  float s0 = bf2f((short)hv.x) + bf2f((short)dv.x);
  float s1 = bf2f((short)hv.y) + bf2f((short)dv.y);
  float s2 = bf2f((short)hv.z) + bf2f((short)dv.z);
  float s3 = bf2f((short)hv.w) + bf2f((short)dv.w);
  float ls = s0 + s1 + s2 + s3;
  float l2 = s0 * s0 + s1 * s1 + s2 * s2 + s3 * s3;
#pragma unroll
  for (int off = 32; off > 0; off >>= 1) {
    ls += __shfl_down(ls, off);
    l2 += __shfl_down(l2, off);
  }
  __shared__ float red[8];
  const int wave = tid >> 6, lane = tid & 63;
  if (lane == 0) { red[wave * 2] = ls; red[wave * 2 + 1] = l2; }
  __syncthreads();
  if (tid == 0) {
    float a = 0.f, b2 = 0.f;
    for (int w = 0; w < 4; ++w) { a += red[w * 2]; b2 += red[w * 2 + 1]; }
    red[0] = a; red[1] = b2;
  }
  __syncthreads();
  const float mean = red[0] * (1.f / HD);
  const float var  = red[1] * (1.f / HD) - mean * mean;
  const float inv  = rsqrtf(var + 1e-5f);
  const f32x4 gv = *(const f32x4*)(g + tid * 4);
  const f32x4 bv = *(const f32x4*)(bb + tid * 4);
  u16x4 y;
  y.x = (unsigned short)f2bf((s0 - mean) * inv * gv.x + bv.x);
  y.y = (unsigned short)f2bf((s1 - mean) * inv * gv.y + bv.y);
  y.z = (unsigned short)f2bf((s2 - mean) * inv * gv.z + bv.z);
  y.w = (unsigned short)f2bf((s3 - mean) * inv * gv.w + bv.w);
  *(u16x4*)(hout + (size_t)r * HD + tid * 4) = y;
}

// ---- pred write + gather cand + cand_out[..,1:] + dbuf = bf16(cand-pred) ----
__global__ __launch_bounds__(256) void gather_cand(const float* __restrict__ outb,
                                                   const int* __restrict__ indices,
                                                   const float* __restrict__ KB,
                                                   float* __restrict__ pred,
                                                   float* __restrict__ cand_out,
                                                   short* __restrict__ dbuf) {
  const int bs = blockIdx.x;
  const int b = bs >> 7, s = bs & 127;
  const int c = threadIdx.x;
  const float p = outb[((size_t)b * SEQ + s + 1) * OUT_DIM + c];
  pred[(size_t)bs * OUT_DIM + c] = p;
  const int* idxp = indices + (size_t)bs * KC;
  for (int k = 0; k < KC; ++k) {
    int idx = idxp[k];
    if (idx < 0) idx = 0;
    const float cv = KB[(size_t)idx * OUT_DIM + c];
    const size_t row = (size_t)bs * KC + k;
    cand_out[row * 257 + 1 + c] = cv;
    dbuf[row * OUT_DIM + c] = f2bf(cv - p);
  }
}

extern "C" void kernel_launch(void* const* d_in, const int* in_sizes, int n_in,
                              void* d_out, int out_size, void* d_ws, size_t ws_size,
                              hipStream_t stream) {
  const float* x      = (const float*)d_in[0];
  const float* ctx    = (const float*)d_in[1];
  const int*   indices= (const int*)d_in[2];
  const float* KB     = (const float*)d_in[3];
  const float* W_in   = (const float*)d_in[4];
  const float* b_in   = (const float*)d_in[5];
  const float* Wqkv   = (const float*)d_in[6];
  const float* bqkv   = (const float*)d_in[7];
  const float* Wo     = (const float*)d_in[8];
  const float* bo     = (const float*)d_in[9];
  const float* ln1_g  = (const float*)d_in[10];
  const float* ln1_b  = (const float*)d_in[11];
  const float* W1     = (const float*)d_in[12];
  const float* b1     = (const float*)d_in[13];
  const float* W2     = (const float*)d_in[14];
  const float* b2     = (const float*)d_in[15];
  const float* ln2_g  = (const float*)d_in[16];
  const float* ln2_b  = (const float*)d_in[17];
  const float* W_out  = (const float*)d_in[18];
  const float* b_out  = (const float*)d_in[19];
  const float* ds_W1  = (const float*)d_in[20];
  const float* ds_b1  = (const float*)d_in[21];
  const float* ds_W2  = (const float*)d_in[22];
  const float* ds_b2  = (const float*)d_in[23];
  // d_in[24..27] = cs_* : dead code in reference (del cs)

  char* p = (char*)d_ws;
  auto alloc = [&](size_t bytes) {
    char* q = p;
    p += (bytes + 255) & ~(size_t)255;
    return q;
  };
  short* h    = (short*)alloc((size_t)MPAD * HD * 2);
  short* tmp1 = (short*)alloc((size_t)MPAD * 3 * HD * 2);  // qkv / ff1
  short* tmp2 = (short*)alloc((size_t)MPAD * HD * 2);      // hin / attn-o
  short* tmp3 = (short*)alloc((size_t)MPAD * HD * 2);      // Wo out / ff2
  float* outb = (float*)alloc((size_t)MROWS * OUT_DIM * 4);
  short* dbuf = (short*)alloc((size_t)NCAND * OUT_DIM * 2);
  short* WinT  = (short*)alloc((size_t)HD * IN_DIM * 2);
  short* WqkvT = (short*)alloc((size_t)2 * 3 * HD * HD * 2);
  short* WoT   = (short*)alloc((size_t)2 * HD * HD * 2);
  short* W1T   = (short*)alloc((size_t)2 * DFF * HD * 2);
  short* W2T   = (short*)alloc((size_t)2 * HD * DFF * 2);
  short* WoutT = (short*)alloc((size_t)OUT_DIM * HD * 2);
  short* dsW1T = (short*)alloc((size_t)OUT_DIM * OUT_DIM * 2);

  // all weight transposes (f32 -> bf16, N x K) in ONE dispatch
  transpose_all<<<17728, 256, 0, stream>>>(W_in, Wqkv, Wo, W1, W2, W_out, ds_W1,
                                           WinT, WqkvT, WoT, W1T, W2T, WoutT, dsW1T);

  // forward
  build_hin<<<MROWS, 256, 0, stream>>>(x, ctx, tmp2);
  gemm_bt<1, 256, short><<<17 * 4, 512, 0, stream>>>(
      tmp2, WinT, b_in, h, MROWS, 1024, 1024, 17, 4, 4, nullptr, nullptr);

  for (int l = 0; l < 2; ++l) {
    gemm_bt<0, 256, short><<<17 * 12, 512, 0, stream>>>(
        h, WqkvT + (size_t)l * 3072 * 1024, bqkv + l * 3072, tmp1,
        MROWS, 3072, 1024, 17, 12, 4, nullptr, nullptr);
    attention_kern<<<dim3(SEQ, NHEAD), 128, 0, stream>>>(tmp1, tmp2);
    gemm_bt<0, 256, short><<<17 * 4, 512, 0, stream>>>(
        tmp2, WoT + (size_t)l * 1024 * 1024, bo + l * 1024, tmp3,
        MROWS, 1024, 1024, 17, 4, 4, nullptr, nullptr);
    add_ln<<<MROWS, 256, 0, stream>>>(h, tmp3, ln1_g + l * 1024, ln1_b + l * 1024, h);
    gemm_bt<1, 256, short><<<17 * 8, 512, 0, stream>>>(
        h, W1T + (size_t)l * 2048 * 1024, b1 + l * 2048, tmp1,
        MROWS, 2048, 1024, 17, 8, 4, nullptr, nullptr);
    gemm_bt<0, 256, short><<<17 * 4, 512, 0, stream>>>(
        tmp1, W2T + (size_t)l * 1024 * 2048, b2 + l * 1024, tmp3,
        MROWS, 1024, 2048, 17, 4, 4, nullptr, nullptr);
    add_ln<<<MROWS, 256, 0, stream>>>(h, tmp3, ln2_g + l * 1024, ln2_b + l * 1024, h);
  }

  gemm_bt<0, 128, float><<<33 * 1, 512, 0, stream>>>(
      h, WoutT, b_out, outb, MROWS, 256, 1024, 33, 1, 33, nullptr, nullptr);

  float* pred = (float*)d_out;
  float* cand_out = (float*)d_out + (size_t)B_ * S_ * OUT_DIM;
  gather_cand<<<4096, 256, 0, stream>>>(outb, indices, KB, pred, cand_out, dbuf);
  // ds GEMM with fused score epilogue: writes cand_out[row*257] directly
  gemm_bt<2, 128, float><<<320 * 1, 512, 0, stream>>>(
      dbuf, dsW1T, ds_b1, cand_out, NCAND, 256, 256, 320, 1, 320, ds_W2, ds_b2);
}

// Round 8
// 565.298 us; speedup vs baseline: 1.1608x; 1.1593x over previous
//
#include <hip/hip_runtime.h>
#include <hip/hip_bf16.h>

typedef __attribute__((ext_vector_type(4))) float f32x4;
typedef __attribute__((ext_vector_type(8))) short s16x8;
typedef __attribute__((ext_vector_type(4))) unsigned short u16x4;

#define B_      32
#define S_      128
#define SEQ     129
#define IN_DIM  1024
#define HD      1024
#define NHEAD   8
#define DH      128
#define OUT_DIM 256
#define KC      10
#define DFF     2048
#define MROWS   (B_*SEQ)     // 4128
#define MPAD    4224         // 33 * 128
#define NCAND   (B_*S_*KC)   // 40960 = 320*128

__device__ __forceinline__ short f2bf(float f) {
  unsigned u = __builtin_bit_cast(unsigned, f);
  u += 0x7FFFu + ((u >> 16) & 1u);   // RNE to bf16
  return (short)(u >> 16);
}
__device__ __forceinline__ float bf2f(short s) {
  return __builtin_bit_cast(float, ((unsigned)(unsigned short)s) << 16);
}
__device__ __forceinline__ void gload16(const short* g, short* l) {
  __builtin_amdgcn_global_load_lds(
      (const __attribute__((address_space(1))) unsigned*)g,
      (__attribute__((address_space(3))) unsigned*)l, 16, 0, 0);
}

// ---------------- ALL weight transposes fused: W[K][N] f32 -> Wt[N][K] bf16 --
__global__ __launch_bounds__(256) void transpose_all(
    const float* __restrict__ W_in,  const float* __restrict__ Wqkv,
    const float* __restrict__ Wo,    const float* __restrict__ W1,
    const float* __restrict__ W2,    const float* __restrict__ W_out,
    const float* __restrict__ dsW1,
    short* __restrict__ WinT,  short* __restrict__ WqkvT,
    short* __restrict__ WoT,   short* __restrict__ W1T,
    short* __restrict__ W2T,   short* __restrict__ WoutT,
    short* __restrict__ dsW1T) {
  const int b = blockIdx.x;
  const float* src; short* dst; int K, N, local;
  if (b < 1024)       { src = W_in;  dst = WinT;  K = 1024; N = 1024; local = b; }
  else if (b < 7168)  { int l = (b - 1024) / 3072; local = (b - 1024) % 3072;
                        src = Wqkv + (size_t)l * 1024 * 3072;
                        dst = WqkvT + (size_t)l * 3072 * 1024; K = 1024; N = 3072; }
  else if (b < 9216)  { int l = (b - 7168) / 1024; local = (b - 7168) % 1024;
                        src = Wo + (size_t)l * 1024 * 1024;
                        dst = WoT + (size_t)l * 1024 * 1024; K = 1024; N = 1024; }
  else if (b < 13312) { int l = (b - 9216) / 2048; local = (b - 9216) % 2048;
                        src = W1 + (size_t)l * 1024 * 2048;
                        dst = W1T + (size_t)l * 2048 * 1024; K = 1024; N = 2048; }
  else if (b < 17408) { int l = (b - 13312) / 2048; local = (b - 13312) % 2048;
                        src = W2 + (size_t)l * 2048 * 1024;
                        dst = W2T + (size_t)l * 1024 * 2048; K = 2048; N = 1024; }
  else if (b < 17664) { local = b - 17408; src = W_out; dst = WoutT; K = 1024; N = 256; }
  else                { local = b - 17664; src = dsW1;  dst = dsW1T; K = 256;  N = 256; }
  const int tilesX = N >> 5;
  const int n0 = (local % tilesX) << 5, k0 = (local / tilesX) << 5;

  __shared__ float tile[32][33];
  const int tx = threadIdx.x & 31, ty = threadIdx.x >> 5;  // 32 x 8
#pragma unroll
  for (int i = 0; i < 4; ++i)
    tile[ty + i * 8][tx] = src[(size_t)(k0 + ty + i * 8) * N + n0 + tx];
  __syncthreads();
#pragma unroll
  for (int i = 0; i < 4; ++i)
    dst[(size_t)(n0 + ty + i * 8) * K + k0 + tx] = f2bf(tile[tx][ty + i * 8]);
}

// ---------------- GEMM: C[M][N] = A[M][K](bf16) * Bt[N][K](bf16) + bias ------
// 128x128 tile, 4 waves, 2-phase LDS double-buffer via global_load_lds with
// pre-swizzled source. XCD-chunked (m204) + groupM order.
// SPLIT=true: grid gm*gn*nsplit; each split computes kper K-columns and
// writes f32 partials to P[split][MPAD][N] (no bias). Reduced by reduce_cast.
// A rows [bm, bm+128) must be readable (M padded). N%128==0, kper%64==0.
template <int EPI, bool SPLIT, typename OutT>
__global__ __launch_bounds__(256) void gemm_bt(const short* __restrict__ A,
                                               const short* __restrict__ Bt,
                                               const float* __restrict__ bias,
                                               OutT* __restrict__ C,
                                               float* __restrict__ P,
                                               int M, int N, int K,
                                               int gm, int gn, int groupM,
                                               int kper) {
  __shared__ alignas(16) short As0[4096], As1[4096];  // 128 rows x 32 bf16
  __shared__ alignas(16) short Bs0[4096], Bs1[4096];
  const int tid = threadIdx.x;
  const int lane = tid & 63, wave = tid >> 6;
  const int wr = wave >> 1, wc = wave & 1;          // 2x2 waves, 64x64 each

  // --- split decode (split-major) + XCD-chunked bijective remap (m204) ------
  const int nwg = gm * gn;
  int orig = blockIdx.x;
  int split = 0;
  if constexpr (SPLIT) { split = orig / nwg; orig %= nwg; }
  const int xcd = orig & 7, kk = orig >> 3;
  const int q = nwg >> 3, r = nwg & 7;
  const int wg = (xcd < r ? xcd * (q + 1) : r * (q + 1) + (xcd - r) * q) + kk;
  const int tpg = groupM * gn;
  const int grp = wg / tpg, rem = wg % tpg;
  const int g0 = grp * groupM;
  const int gsz = (groupM < gm - g0) ? groupM : (gm - g0);
  const int bm = (g0 + rem % gsz) * 128;
  const int bn = (rem / gsz) * 128;
  const int kbase = SPLIT ? split * kper : 0;

  // staging: pre-swizzled global source, linear LDS dest (global_load_lds).
  // idx = i*256 + tid; row rr = idx>>2; lds 16B-slot ss = idx&3;
  // global 16B-slot gg = ss ^ ((rr>>1)&3)
  const short* pa[2];
  const short* pb[2];
#pragma unroll
  for (int i = 0; i < 2; ++i) {
    const int idx = i * 256 + tid;
    const int rr = idx >> 2, ss = idx & 3, gg = ss ^ ((rr >> 1) & 3);
    pa[i] = A + (size_t)(bm + rr) * K + kbase + gg * 8;
    pb[i] = Bt + (size_t)(bn + rr) * K + kbase + gg * 8;
  }

  auto stage = [&](short* aBuf, short* bBuf, int t) {
    const int kofs = t << 5;
    gload16(pa[0] + kofs, aBuf + wave * 512);
    gload16(pa[1] + kofs, aBuf + 2048 + wave * 512);
    gload16(pb[0] + kofs, bBuf + wave * 512);
    gload16(pb[1] + kofs, bBuf + 2048 + wave * 512);
  };

  // fragment reads (swizzled): row rr, k-slot ks -> shorts rr*32 + ((ks^sx)<<3)
  const int lrow = lane & 15, ks = lane >> 4;
  const int sx = (lrow >> 1) & 3;
  const int koff = ((ks ^ sx) << 3);

  f32x4 acc[4][4] = {};

  auto compute = [&](const short* as, const short* bs) {
    s16x8 af[4], bfr[4];
#pragma unroll
    for (int m = 0; m < 4; ++m)
      af[m] = *(const s16x8*)&as[(wr * 64 + m * 16 + lrow) * 32 + koff];
#pragma unroll
    for (int n = 0; n < 4; ++n)
      bfr[n] = *(const s16x8*)&bs[(wc * 64 + n * 16 + lrow) * 32 + koff];
#pragma unroll
    for (int m = 0; m < 4; ++m)
#pragma unroll
      for (int n = 0; n < 4; ++n)
        asm("v_mfma_f32_16x16x32_bf16 %0, %1, %2, %0"
            : "+v"(acc[m][n]) : "v"(af[m]), "v"(bfr[n]));
  };

  const int NT = (SPLIT ? kper : K) >> 5;   // even at all call sites
  stage(As0, Bs0, 0);
  __syncthreads();
  for (int t = 0; t < NT; t += 2) {
    stage(As1, Bs1, t + 1);              // prefetch overlaps compute below
    compute(As0, Bs0);
    __syncthreads();
    if (t + 2 < NT) stage(As0, Bs0, t + 2);
    compute(As1, Bs1);
    __syncthreads();
  }

  const int lg4 = ks << 2;
#pragma unroll
  for (int n = 0; n < 4; ++n) {
    const int col = bn + wc * 64 + n * 16 + lrow;
    const float bvx = SPLIT ? 0.f : bias[col];
#pragma unroll
    for (int m = 0; m < 4; ++m) {
#pragma unroll
      for (int r2 = 0; r2 < 4; ++r2) {
        const int row = bm + wr * 64 + m * 16 + lg4 + r2;
        if constexpr (SPLIT) {
          P[((size_t)split * MPAD + row) * N + col] = acc[m][n][r2];
        } else {
          if (row < M) {
            float v = acc[m][n][r2] + bvx;
            if (EPI == 1) v = fmaxf(v, 0.f);
            if constexpr (__is_same(OutT, float)) {
              C[(size_t)row * N + col] = v;
            } else {
              C[(size_t)row * N + col] = f2bf(v);
            }
          }
        }
      }
    }
  }
}

// ---------------- reduce split-K partials: out = f(sum_s P[s] + bias) --------
template <int EPI, typename OutT>
__global__ __launch_bounds__(256) void reduce_cast(const float* __restrict__ P,
                                                   const float* __restrict__ bias,
                                                   OutT* __restrict__ out,
                                                   int N, int nsplit) {
  const int row = blockIdx.x;            // 0..MROWS-1
  for (int c = threadIdx.x * 4; c < N; c += 1024) {
    f32x4 s = *(const f32x4*)(P + (size_t)row * N + c);
    for (int sp = 1; sp < nsplit; ++sp)
      s += *(const f32x4*)(P + ((size_t)sp * MPAD + row) * N + c);
    s += *(const f32x4*)(bias + c);
    if (EPI == 1) {
      s.x = fmaxf(s.x, 0.f); s.y = fmaxf(s.y, 0.f);
      s.z = fmaxf(s.z, 0.f); s.w = fmaxf(s.w, 0.f);
    }
    if constexpr (__is_same(OutT, float)) {
      *(f32x4*)(out + (size_t)row * N + c) = s;
    } else {
      u16x4 y;
      y.x = (unsigned short)f2bf(s.x); y.y = (unsigned short)f2bf(s.y);
      y.z = (unsigned short)f2bf(s.z); y.w = (unsigned short)f2bf(s.w);
      *(u16x4*)(out + (size_t)row * N + c) = y;
    }
  }
}

// ---------------- build h_in = concat([ctx, x], axis=1) -> bf16 --------------
__global__ __launch_bounds__(256) void build_hin(const float* __restrict__ x,
                                                 const float* __restrict__ ctx,
                                                 short* __restrict__ hin) {
  const int r = blockIdx.x;
  const int b = r / SEQ, t = r % SEQ;
  const float* src = (t == 0) ? (ctx + (size_t)b * IN_DIM)
                              : (x + ((size_t)b * S_ + (t - 1)) * IN_DIM);
  f32x4 v = *(const f32x4*)(src + threadIdx.x * 4);
  u16x4 o;
  o.x = (unsigned short)f2bf(v.x); o.y = (unsigned short)f2bf(v.y);
  o.z = (unsigned short)f2bf(v.z); o.w = (unsigned short)f2bf(v.w);
  *(u16x4*)(hin + (size_t)r * IN_DIM + threadIdx.x * 4) = o;
}

// ---------------- attention over batch axis (32) at each (pos t, head) ------
__global__ __launch_bounds__(128) void attention_kern(const short* __restrict__ qkv,
                                                      short* __restrict__ o) {
  __shared__ alignas(16) float qs[32][132], ksm[32][132], vs[32][132];
  __shared__ float ps[32][33];
  const int t = blockIdx.x, hd = blockIdx.y, tid = threadIdx.x;
  for (int i = tid; i < 32 * 16; i += 128) {   // 32 rows x 16 chunks of 8 bf16
    const int bb = i >> 4, d8 = (i & 15) << 3;
    const size_t base = (size_t)(bb * SEQ + t) * (3 * HD) + hd * DH + d8;
    s16x8 q8 = *(const s16x8*)(qkv + base);
    s16x8 k8 = *(const s16x8*)(qkv + base + HD);
    s16x8 v8 = *(const s16x8*)(qkv + base + 2 * HD);
#pragma unroll
    for (int j = 0; j < 8; ++j) {
      qs[bb][d8 + j] = bf2f(q8[j]);
      ksm[bb][d8 + j] = bf2f(k8[j]);
      vs[bb][d8 + j] = bf2f(v8[j]);
    }
  }
  __syncthreads();
  const float scale = 0.08838834764831845f;   // 1/sqrt(128)
  for (int idx = tid; idx < 1024; idx += 128) {
    const int i = idx >> 5, j = idx & 31;
    float s = 0.f;
#pragma unroll 8
    for (int d = 0; d < DH; ++d) s += qs[i][d] * ksm[j][d];
    ps[i][j] = s * scale;
  }
  __syncthreads();
  if (tid < 32) {
    float mx = -1e30f;
#pragma unroll
    for (int j = 0; j < 32; ++j) mx = fmaxf(mx, ps[tid][j]);
    float sum = 0.f;
#pragma unroll
    for (int j = 0; j < 32; ++j) { float e = __expf(ps[tid][j] - mx); ps[tid][j] = e; sum += e; }
    const float inv = 1.f / sum;
#pragma unroll
    for (int j = 0; j < 32; ++j) ps[tid][j] *= inv;
  }
  __syncthreads();
  for (int idx = tid; idx < 32 * DH; idx += 128) {
    const int i = idx >> 7, d = idx & 127;
    float s = 0.f;
#pragma unroll
    for (int j = 0; j < 32; ++j) s += ps[i][j] * vs[j][d];
    o[(size_t)(i * SEQ + t) * HD + hd * DH + d] = f2bf(s);
  }
}

// ---------------- y = LN(h + delta) * g + b  (bf16 in / bf16 out) -----------
__global__ __launch_bounds__(256) void add_ln(const short* __restrict__ hin,
                                              const short* __restrict__ delta,
                                              const float* __restrict__ g,
                                              const float* __restrict__ bb,
                                              short* __restrict__ hout) {
  const int r = blockIdx.x, tid = threadIdx.x;
  const u16x4 hv = *(const u16x4*)(hin + (size_t)r * HD + tid * 4);
  const u16x4 dv = *(const u16x4*)(delta + (size_t)r * HD + tid * 4);
  float s0 = bf2f((short)hv.x) + bf2f((short)dv.x);
  float s1 = bf2f((short)hv.y) + bf2f((short)dv.y);
  float s2 = bf2f((short)hv.z) + bf2f((short)dv.z);
  float s3 = bf2f((short)hv.w) + bf2f((short)dv.w);
  float ls = s0 + s1 + s2 + s3;
  float l2 = s0 * s0 + s1 * s1 + s2 * s2 + s3 * s3;
#pragma unroll
  for (int off = 32; off > 0; off >>= 1) {
    ls += __shfl_down(ls, off);
    l2 += __shfl_down(l2, off);
  }
  __shared__ float red[8];
  const int wave = tid >> 6, lane = tid & 63;
  if (lane == 0) { red[wave * 2] = ls; red[wave * 2 + 1] = l2; }
  __syncthreads();
  if (tid == 0) {
    float a = 0.f, b2 = 0.f;
    for (int w = 0; w < 4; ++w) { a += red[w * 2]; b2 += red[w * 2 + 1]; }
    red[0] = a; red[1] = b2;
  }
  __syncthreads();
  const float mean = red[0] * (1.f / HD);
  const float var  = red[1] * (1.f / HD) - mean * mean;
  const float inv  = rsqrtf(var + 1e-5f);
  const f32x4 gv = *(const f32x4*)(g + tid * 4);
  const f32x4 bv = *(const f32x4*)(bb + tid * 4);
  u16x4 y;
  y.x = (unsigned short)f2bf((s0 - mean) * inv * gv.x + bv.x);
  y.y = (unsigned short)f2bf((s1 - mean) * inv * gv.y + bv.y);
  y.z = (unsigned short)f2bf((s2 - mean) * inv * gv.z + bv.z);
  y.w = (unsigned short)f2bf((s3 - mean) * inv * gv.w + bv.w);
  *(u16x4*)(hout + (size_t)r * HD + tid * 4) = y;
}

// ---- pred write + gather cand + cand_out[..,1:] + dbuf = bf16(cand-pred) ----
__global__ __launch_bounds__(256) void gather_cand(const float* __restrict__ outb,
                                                   const int* __restrict__ indices,
                                                   const float* __restrict__ KB,
                                                   float* __restrict__ pred,
                                                   float* __restrict__ cand_out,
                                                   short* __restrict__ dbuf) {
  const int bs = blockIdx.x;
  const int b = bs >> 7, s = bs & 127;
  const int c = threadIdx.x;
  const float p = outb[((size_t)b * SEQ + s + 1) * OUT_DIM + c];
  pred[(size_t)bs * OUT_DIM + c] = p;
  const int* idxp = indices + (size_t)bs * KC;
  for (int k = 0; k < KC; ++k) {
    int idx = idxp[k];
    if (idx < 0) idx = 0;
    const float cv = KB[(size_t)idx * OUT_DIM + c];
    const size_t row = (size_t)bs * KC + k;
    cand_out[row * 257 + 1 + c] = cv;
    dbuf[row * OUT_DIM + c] = f2bf(cv - p);
  }
}

// ---------------- ds = t1(bf16, relu'd) . W2 + b2 -> cand_out[row*257] ------
__global__ __launch_bounds__(256) void score_reduce(const short* __restrict__ t1,
                                                    const float* __restrict__ W2,
                                                    const float* __restrict__ b2,
                                                    float* __restrict__ cand_out) {
  const int wave = threadIdx.x >> 6, lane = threadIdx.x & 63;
  const size_t row = (size_t)blockIdx.x * 4 + wave;
  const short* tp = t1 + row * OUT_DIM;
  float sum = 0.f;
  for (int c = lane; c < OUT_DIM; c += 64) sum += bf2f(tp[c]) * W2[c];
#pragma unroll
  for (int off = 32; off > 0; off >>= 1) sum += __shfl_down(sum, off);
  if (lane == 0) cand_out[row * 257] = sum + b2[0];
}

extern "C" void kernel_launch(void* const* d_in, const int* in_sizes, int n_in,
                              void* d_out, int out_size, void* d_ws, size_t ws_size,
                              hipStream_t stream) {
  const float* x      = (const float*)d_in[0];
  const float* ctx    = (const float*)d_in[1];
  const int*   indices= (const int*)d_in[2];
  const float* KB     = (const float*)d_in[3];
  const float* W_in   = (const float*)d_in[4];
  const float* b_in   = (const float*)d_in[5];
  const float* Wqkv   = (const float*)d_in[6];
  const float* bqkv   = (const float*)d_in[7];
  const float* Wo     = (const float*)d_in[8];
  const float* bo     = (const float*)d_in[9];
  const float* ln1_g  = (const float*)d_in[10];
  const float* ln1_b  = (const float*)d_in[11];
  const float* W1     = (const float*)d_in[12];
  const float* b1     = (const float*)d_in[13];
  const float* W2     = (const float*)d_in[14];
  const float* b2     = (const float*)d_in[15];
  const float* ln2_g  = (const float*)d_in[16];
  const float* ln2_b  = (const float*)d_in[17];
  const float* W_out  = (const float*)d_in[18];
  const float* b_out  = (const float*)d_in[19];
  const float* ds_W1  = (const float*)d_in[20];
  const float* ds_b1  = (const float*)d_in[21];
  const float* ds_W2  = (const float*)d_in[22];
  const float* ds_b2  = (const float*)d_in[23];
  // d_in[24..27] = cs_* : dead code in reference (del cs)

  char* p = (char*)d_ws;
  auto alloc = [&](size_t bytes) {
    char* q = p;
    p += (bytes + 255) & ~(size_t)255;
    return q;
  };
  short* h    = (short*)alloc((size_t)MPAD * HD * 2);
  short* tmp1 = (short*)alloc((size_t)MPAD * 3 * HD * 2);  // qkv / ff1
  short* tmp2 = (short*)alloc((size_t)MPAD * HD * 2);      // hin / attn-o
  short* tmp3 = (short*)alloc((size_t)MPAD * HD * 2);      // Wo out / ff2
  float* outb = (float*)alloc((size_t)MROWS * OUT_DIM * 4);
  short* dbuf = (short*)alloc((size_t)NCAND * OUT_DIM * 2);
  short* t1   = (short*)alloc((size_t)NCAND * OUT_DIM * 2);
  short* WinT  = (short*)alloc((size_t)HD * IN_DIM * 2);
  short* WqkvT = (short*)alloc((size_t)2 * 3 * HD * HD * 2);
  short* WoT   = (short*)alloc((size_t)2 * HD * HD * 2);
  short* W1T   = (short*)alloc((size_t)2 * DFF * HD * 2);
  short* W2T   = (short*)alloc((size_t)2 * HD * DFF * 2);
  short* WoutT = (short*)alloc((size_t)OUT_DIM * HD * 2);
  short* dsW1T = (short*)alloc((size_t)OUT_DIM * OUT_DIM * 2);

  // split-K partial buffer: ALIASED onto dbuf+t1 (42 MB region, need 34.6 MB).
  // Partials are dead before gather_cand writes dbuf / ds GEMM writes t1.
  float* part = (float*)dbuf;

  // all weight transposes (f32 -> bf16, N x K) in ONE dispatch
  transpose_all<<<17728, 256, 0, stream>>>(W_in, Wqkv, Wo, W1, W2, W_out, ds_W1,
                                           WinT, WqkvT, WoT, W1T, W2T, WoutT, dsW1T);

  // forward
  build_hin<<<MROWS, 256, 0, stream>>>(x, ctx, tmp2);
  // Win: split-K x2 (528 blocks), then reduce+bias+relu -> h (bf16)
  gemm_bt<0, true, short><<<33 * 8 * 2, 256, 0, stream>>>(
      tmp2, WinT, nullptr, nullptr, part, MROWS, 1024, 1024, 33, 8, 8, 512);
  reduce_cast<1, short><<<MROWS, 256, 0, stream>>>(part, b_in, h, 1024, 2);

  for (int l = 0; l < 2; ++l) {
    gemm_bt<0, false, short><<<33 * 24, 256, 0, stream>>>(
        h, WqkvT + (size_t)l * 3072 * 1024, bqkv + l * 3072, tmp1, nullptr,
        MROWS, 3072, 1024, 33, 24, 8, 0);
    attention_kern<<<dim3(SEQ, NHEAD), 128, 0, stream>>>(tmp1, tmp2);
    // Wo: split-K x2
    gemm_bt<0, true, short><<<33 * 8 * 2, 256, 0, stream>>>(
        tmp2, WoT + (size_t)l * 1024 * 1024, nullptr, nullptr, part,
        MROWS, 1024, 1024, 33, 8, 8, 512);
    reduce_cast<0, short><<<MROWS, 256, 0, stream>>>(part, bo + l * 1024, tmp3, 1024, 2);
    add_ln<<<MROWS, 256, 0, stream>>>(h, tmp3, ln1_g + l * 1024, ln1_b + l * 1024, h);
    gemm_bt<1, false, short><<<33 * 16, 256, 0, stream>>>(
        h, W1T + (size_t)l * 2048 * 1024, b1 + l * 2048, tmp1, nullptr,
        MROWS, 2048, 1024, 33, 16, 8, 0);
    // W2: split-K x2 (K=2048 -> 1024 each)
    gemm_bt<0, true, short><<<33 * 8 * 2, 256, 0, stream>>>(
        tmp1, W2T + (size_t)l * 1024 * 2048, nullptr, nullptr, part,
        MROWS, 1024, 2048, 33, 8, 4, 1024);
    reduce_cast<0, short><<<MROWS, 256, 0, stream>>>(part, b2 + l * 1024, tmp3, 1024, 2);
    add_ln<<<MROWS, 256, 0, stream>>>(h, tmp3, ln2_g + l * 1024, ln2_b + l * 1024, h);
  }

  // Wout: split-K x4 (264 blocks), reduce -> outb (f32)
  gemm_bt<0, true, float><<<33 * 2 * 4, 256, 0, stream>>>(
      h, WoutT, nullptr, nullptr, part, MROWS, 256, 1024, 33, 2, 8, 256);
  reduce_cast<0, float><<<MROWS, 256, 0, stream>>>(part, b_out, outb, 256, 4);

  float* pred = (float*)d_out;
  float* cand_out = (float*)d_out + (size_t)B_ * S_ * OUT_DIM;
  gather_cand<<<4096, 256, 0, stream>>>(outb, indices, KB, pred, cand_out, dbuf);
  gemm_bt<1, false, short><<<320 * 2, 256, 0, stream>>>(
      dbuf, dsW1T, ds_b1, t1, nullptr, NCAND, 256, 256, 320, 2, 16, 0);
  score_reduce<<<NCAND / 4, 256, 0, stream>>>(t1, ds_W2, ds_b2, cand_out);
}

// Round 9
// 511.201 us; speedup vs baseline: 1.2837x; 1.1058x over previous
//
#include <hip/hip_runtime.h>
#include <hip/hip_bf16.h>

typedef __attribute__((ext_vector_type(4))) float f32x4;
typedef __attribute__((ext_vector_type(8))) short s16x8;
typedef __attribute__((ext_vector_type(4))) unsigned short u16x4;

#define B_      32
#define S_      128
#define SEQ     129
#define IN_DIM  1024
#define HD      1024
#define NHEAD   8
#define DH      128
#define OUT_DIM 256
#define KC      10
#define DFF     2048
#define MROWS   (B_*SEQ)     // 4128
#define MPAD    4224         // 33 * 128
#define NCAND   (B_*S_*KC)   // 40960 = 640*64

__device__ __forceinline__ short f2bf(float f) {
  unsigned u = __builtin_bit_cast(unsigned, f);
  u += 0x7FFFu + ((u >> 16) & 1u);   // RNE to bf16
  return (short)(u >> 16);
}
__device__ __forceinline__ float bf2f(short s) {
  return __builtin_bit_cast(float, ((unsigned)(unsigned short)s) << 16);
}
__device__ __forceinline__ void gload16(const short* g, short* l) {
  __builtin_amdgcn_global_load_lds(
      (const __attribute__((address_space(1))) unsigned*)g,
      (__attribute__((address_space(3))) unsigned*)l, 16, 0, 0);
}

// ---------------- ALL weight transposes fused: W[K][N] f32 -> Wt[N][K] bf16 --
__global__ __launch_bounds__(256) void transpose_all(
    const float* __restrict__ W_in,  const float* __restrict__ Wqkv,
    const float* __restrict__ Wo,    const float* __restrict__ W1,
    const float* __restrict__ W2,    const float* __restrict__ W_out,
    const float* __restrict__ dsW1,
    short* __restrict__ WinT,  short* __restrict__ WqkvT,
    short* __restrict__ WoT,   short* __restrict__ W1T,
    short* __restrict__ W2T,   short* __restrict__ WoutT,
    short* __restrict__ dsW1T) {
  const int b = blockIdx.x;
  const float* src; short* dst; int K, N, local;
  if (b < 1024)       { src = W_in;  dst = WinT;  K = 1024; N = 1024; local = b; }
  else if (b < 7168)  { int l = (b - 1024) / 3072; local = (b - 1024) % 3072;
                        src = Wqkv + (size_t)l * 1024 * 3072;
                        dst = WqkvT + (size_t)l * 3072 * 1024; K = 1024; N = 3072; }
  else if (b < 9216)  { int l = (b - 7168) / 1024; local = (b - 7168) % 1024;
                        src = Wo + (size_t)l * 1024 * 1024;
                        dst = WoT + (size_t)l * 1024 * 1024; K = 1024; N = 1024; }
  else if (b < 13312) { int l = (b - 9216) / 2048; local = (b - 9216) % 2048;
                        src = W1 + (size_t)l * 1024 * 2048;
                        dst = W1T + (size_t)l * 2048 * 1024; K = 1024; N = 2048; }
  else if (b < 17408) { int l = (b - 13312) / 2048; local = (b - 13312) % 2048;
                        src = W2 + (size_t)l * 2048 * 1024;
                        dst = W2T + (size_t)l * 1024 * 2048; K = 2048; N = 1024; }
  else if (b < 17664) { local = b - 17408; src = W_out; dst = WoutT; K = 1024; N = 256; }
  else                { local = b - 17664; src = dsW1;  dst = dsW1T; K = 256;  N = 256; }
  const int tilesX = N >> 5;
  const int n0 = (local % tilesX) << 5, k0 = (local / tilesX) << 5;

  __shared__ float tile[32][33];
  const int tx = threadIdx.x & 31, ty = threadIdx.x >> 5;  // 32 x 8
#pragma unroll
  for (int i = 0; i < 4; ++i)
    tile[ty + i * 8][tx] = src[(size_t)(k0 + ty + i * 8) * N + n0 + tx];
  __syncthreads();
#pragma unroll
  for (int i = 0; i < 4; ++i)
    dst[(size_t)(n0 + ty + i * 8) * K + k0 + tx] = f2bf(tile[tx][ty + i * 8]);
}

// ---------------- GEMM: C[M][N] = A[M][K](bf16) * Bt[N][K](bf16) + bias ------
// 128x128 tile, 4 waves, 2-phase LDS double-buffer via global_load_lds with
// pre-swizzled source. XCD-chunked (m204) + groupM order.
// SPLIT=true: grid gm*gn*nsplit; each split computes kper K-columns and
// writes f32 partials to P[split][MPAD][N] (no bias).
template <int EPI, bool SPLIT, typename OutT>
__global__ __launch_bounds__(256) void gemm_bt(const short* __restrict__ A,
                                               const short* __restrict__ Bt,
                                               const float* __restrict__ bias,
                                               OutT* __restrict__ C,
                                               float* __restrict__ P,
                                               int M, int N, int K,
                                               int gm, int gn, int groupM,
                                               int kper) {
  __shared__ alignas(16) short As0[4096], As1[4096];  // 128 rows x 32 bf16
  __shared__ alignas(16) short Bs0[4096], Bs1[4096];
  const int tid = threadIdx.x;
  const int lane = tid & 63, wave = tid >> 6;
  const int wr = wave >> 1, wc = wave & 1;          // 2x2 waves, 64x64 each

  // --- split decode (split-major) + XCD-chunked bijective remap (m204) ------
  const int nwg = gm * gn;
  int orig = blockIdx.x;
  int split = 0;
  if constexpr (SPLIT) { split = orig / nwg; orig %= nwg; }
  const int xcd = orig & 7, kk = orig >> 3;
  const int q = nwg >> 3, r = nwg & 7;
  const int wg = (xcd < r ? xcd * (q + 1) : r * (q + 1) + (xcd - r) * q) + kk;
  const int tpg = groupM * gn;
  const int grp = wg / tpg, rem = wg % tpg;
  const int g0 = grp * groupM;
  const int gsz = (groupM < gm - g0) ? groupM : (gm - g0);
  const int bm = (g0 + rem % gsz) * 128;
  const int bn = (rem / gsz) * 128;
  const int kbase = SPLIT ? split * kper : 0;

  // staging: pre-swizzled global source, linear LDS dest (global_load_lds).
  const short* pa[2];
  const short* pb[2];
#pragma unroll
  for (int i = 0; i < 2; ++i) {
    const int idx = i * 256 + tid;
    const int rr = idx >> 2, ss = idx & 3, gg = ss ^ ((rr >> 1) & 3);
    pa[i] = A + (size_t)(bm + rr) * K + kbase + gg * 8;
    pb[i] = Bt + (size_t)(bn + rr) * K + kbase + gg * 8;
  }

  auto stage = [&](short* aBuf, short* bBuf, int t) {
    const int kofs = t << 5;
    gload16(pa[0] + kofs, aBuf + wave * 512);
    gload16(pa[1] + kofs, aBuf + 2048 + wave * 512);
    gload16(pb[0] + kofs, bBuf + wave * 512);
    gload16(pb[1] + kofs, bBuf + 2048 + wave * 512);
  };

  // fragment reads (swizzled): row rr, k-slot ks -> shorts rr*32 + ((ks^sx)<<3)
  const int lrow = lane & 15, ks = lane >> 4;
  const int sx = (lrow >> 1) & 3;
  const int koff = ((ks ^ sx) << 3);

  f32x4 acc[4][4] = {};

  auto compute = [&](const short* as, const short* bs) {
    s16x8 af[4], bfr[4];
#pragma unroll
    for (int m = 0; m < 4; ++m)
      af[m] = *(const s16x8*)&as[(wr * 64 + m * 16 + lrow) * 32 + koff];
#pragma unroll
    for (int n = 0; n < 4; ++n)
      bfr[n] = *(const s16x8*)&bs[(wc * 64 + n * 16 + lrow) * 32 + koff];
#pragma unroll
    for (int m = 0; m < 4; ++m)
#pragma unroll
      for (int n = 0; n < 4; ++n)
        asm("v_mfma_f32_16x16x32_bf16 %0, %1, %2, %0"
            : "+v"(acc[m][n]) : "v"(af[m]), "v"(bfr[n]));
  };

  const int NT = (SPLIT ? kper : K) >> 5;   // even at all call sites
  stage(As0, Bs0, 0);
  __syncthreads();
  for (int t = 0; t < NT; t += 2) {
    stage(As1, Bs1, t + 1);              // prefetch overlaps compute below
    compute(As0, Bs0);
    __syncthreads();
    if (t + 2 < NT) stage(As0, Bs0, t + 2);
    compute(As1, Bs1);
    __syncthreads();
  }

  const int lg4 = ks << 2;
#pragma unroll
  for (int n = 0; n < 4; ++n) {
    const int col = bn + wc * 64 + n * 16 + lrow;
    const float bvx = SPLIT ? 0.f : bias[col];
#pragma unroll
    for (int m = 0; m < 4; ++m) {
#pragma unroll
      for (int r2 = 0; r2 < 4; ++r2) {
        const int row = bm + wr * 64 + m * 16 + lg4 + r2;
        if constexpr (SPLIT) {
          P[((size_t)split * MPAD + row) * N + col] = acc[m][n][r2];
        } else {
          if (row < M) {
            float v = acc[m][n][r2] + bvx;
            if (EPI == 1) v = fmaxf(v, 0.f);
            if constexpr (__is_same(OutT, float)) {
              C[(size_t)row * N + col] = v;
            } else {
              C[(size_t)row * N + col] = f2bf(v);
            }
          }
        }
      }
    }
  }
}

// ---------------- reduce split-K partials: out = f(sum_s P[s] + bias) --------
template <int EPI, typename OutT>
__global__ __launch_bounds__(256) void reduce_cast(const float* __restrict__ P,
                                                   const float* __restrict__ bias,
                                                   OutT* __restrict__ out,
                                                   int N, int nsplit) {
  const int row = blockIdx.x;            // 0..MROWS-1
  for (int c = threadIdx.x * 4; c < N; c += 1024) {
    f32x4 s = *(const f32x4*)(P + (size_t)row * N + c);
    for (int sp = 1; sp < nsplit; ++sp)
      s += *(const f32x4*)(P + ((size_t)sp * MPAD + row) * N + c);
    s += *(const f32x4*)(bias + c);
    if (EPI == 1) {
      s.x = fmaxf(s.x, 0.f); s.y = fmaxf(s.y, 0.f);
      s.z = fmaxf(s.z, 0.f); s.w = fmaxf(s.w, 0.f);
    }
    if constexpr (__is_same(OutT, float)) {
      *(f32x4*)(out + (size_t)row * N + c) = s;
    } else {
      u16x4 y;
      y.x = (unsigned short)f2bf(s.x); y.y = (unsigned short)f2bf(s.y);
      y.z = (unsigned short)f2bf(s.z); y.w = (unsigned short)f2bf(s.w);
      *(u16x4*)(out + (size_t)row * N + c) = y;
    }
  }
}

// ---- fused: h = LN(h + (P0+P1 + bias)) * g + b  (split-K reduce + add+LN) ---
__global__ __launch_bounds__(256) void reduce_ln(const float* __restrict__ P,
                                                 const float* __restrict__ bias,
                                                 const float* __restrict__ g,
                                                 const float* __restrict__ bb,
                                                 short* __restrict__ h) {
  const int r = blockIdx.x, tid = threadIdx.x;
  f32x4 s = *(const f32x4*)(P + (size_t)r * 1024 + tid * 4);
  s += *(const f32x4*)(P + ((size_t)MPAD + r) * 1024 + tid * 4);
  s += *(const f32x4*)(bias + tid * 4);
  const u16x4 hv = *(const u16x4*)(h + (size_t)r * 1024 + tid * 4);
  float s0 = s.x + bf2f((short)hv.x);
  float s1 = s.y + bf2f((short)hv.y);
  float s2 = s.z + bf2f((short)hv.z);
  float s3 = s.w + bf2f((short)hv.w);
  float ls = s0 + s1 + s2 + s3;
  float l2 = s0 * s0 + s1 * s1 + s2 * s2 + s3 * s3;
#pragma unroll
  for (int off = 32; off > 0; off >>= 1) {
    ls += __shfl_down(ls, off);
    l2 += __shfl_down(l2, off);
  }
  __shared__ float red[8];
  const int wave = tid >> 6, lane = tid & 63;
  if (lane == 0) { red[wave * 2] = ls; red[wave * 2 + 1] = l2; }
  __syncthreads();
  if (tid == 0) {
    float a = 0.f, b2 = 0.f;
    for (int w = 0; w < 4; ++w) { a += red[w * 2]; b2 += red[w * 2 + 1]; }
    red[0] = a; red[1] = b2;
  }
  __syncthreads();
  const float mean = red[0] * (1.f / HD);
  const float var  = red[1] * (1.f / HD) - mean * mean;
  const float inv  = rsqrtf(var + 1e-5f);
  const f32x4 gv = *(const f32x4*)(g + tid * 4);
  const f32x4 bv = *(const f32x4*)(bb + tid * 4);
  u16x4 y;
  y.x = (unsigned short)f2bf((s0 - mean) * inv * gv.x + bv.x);
  y.y = (unsigned short)f2bf((s1 - mean) * inv * gv.y + bv.y);
  y.z = (unsigned short)f2bf((s2 - mean) * inv * gv.z + bv.z);
  y.w = (unsigned short)f2bf((s3 - mean) * inv * gv.w + bv.w);
  *(u16x4*)(h + (size_t)r * 1024 + tid * 4) = y;
}

// ---- Wout reduce (4 splits, N=256) -> outb (f32) AND pred (d_out) ----------
__global__ __launch_bounds__(64) void reduce_wout(const float* __restrict__ P,
                                                  const float* __restrict__ bias,
                                                  float* __restrict__ outb,
                                                  float* __restrict__ pred) {
  const int r = blockIdx.x;
  const int c = threadIdx.x * 4;
  f32x4 s = *(const f32x4*)(P + (size_t)r * 256 + c);
  s += *(const f32x4*)(P + ((size_t)MPAD + r) * 256 + c);
  s += *(const f32x4*)(P + ((size_t)2 * MPAD + r) * 256 + c);
  s += *(const f32x4*)(P + ((size_t)3 * MPAD + r) * 256 + c);
  s += *(const f32x4*)(bias + c);
  *(f32x4*)(outb + (size_t)r * 256 + c) = s;
  const int b = r / SEQ, t = r % SEQ;
  if (t > 0) *(f32x4*)(pred + ((size_t)b * S_ + (t - 1)) * 256 + c) = s;
}

// ---------------- build h_in = concat([ctx, x], axis=1) -> bf16 --------------
__global__ __launch_bounds__(256) void build_hin(const float* __restrict__ x,
                                                 const float* __restrict__ ctx,
                                                 short* __restrict__ hin) {
  const int r = blockIdx.x;
  const int b = r / SEQ, t = r % SEQ;
  const float* src = (t == 0) ? (ctx + (size_t)b * IN_DIM)
                              : (x + ((size_t)b * S_ + (t - 1)) * IN_DIM);
  f32x4 v = *(const f32x4*)(src + threadIdx.x * 4);
  u16x4 o;
  o.x = (unsigned short)f2bf(v.x); o.y = (unsigned short)f2bf(v.y);
  o.z = (unsigned short)f2bf(v.z); o.w = (unsigned short)f2bf(v.w);
  *(u16x4*)(hin + (size_t)r * IN_DIM + threadIdx.x * 4) = o;
}

// ---------------- attention over batch axis (32) at each (pos t, head) ------
__global__ __launch_bounds__(128) void attention_kern(const short* __restrict__ qkv,
                                                      short* __restrict__ o) {
  __shared__ alignas(16) float qs[32][132], ksm[32][132], vs[32][132];
  __shared__ float ps[32][33];
  const int t = blockIdx.x, hd = blockIdx.y, tid = threadIdx.x;
  for (int i = tid; i < 32 * 16; i += 128) {   // 32 rows x 16 chunks of 8 bf16
    const int bb = i >> 4, d8 = (i & 15) << 3;
    const size_t base = (size_t)(bb * SEQ + t) * (3 * HD) + hd * DH + d8;
    s16x8 q8 = *(const s16x8*)(qkv + base);
    s16x8 k8 = *(const s16x8*)(qkv + base + HD);
    s16x8 v8 = *(const s16x8*)(qkv + base + 2 * HD);
#pragma unroll
    for (int j = 0; j < 8; ++j) {
      qs[bb][d8 + j] = bf2f(q8[j]);
      ksm[bb][d8 + j] = bf2f(k8[j]);
      vs[bb][d8 + j] = bf2f(v8[j]);
    }
  }
  __syncthreads();
  const float scale = 0.08838834764831845f;   // 1/sqrt(128)
  for (int idx = tid; idx < 1024; idx += 128) {
    const int i = idx >> 5, j = idx & 31;
    float s = 0.f;
#pragma unroll 8
    for (int d = 0; d < DH; ++d) s += qs[i][d] * ksm[j][d];
    ps[i][j] = s * scale;
  }
  __syncthreads();
  if (tid < 32) {
    float mx = -1e30f;
#pragma unroll
    for (int j = 0; j < 32; ++j) mx = fmaxf(mx, ps[tid][j]);
    float sum = 0.f;
#pragma unroll
    for (int j = 0; j < 32; ++j) { float e = __expf(ps[tid][j] - mx); ps[tid][j] = e; sum += e; }
    const float inv = 1.f / sum;
#pragma unroll
    for (int j = 0; j < 32; ++j) ps[tid][j] *= inv;
  }
  __syncthreads();
  for (int idx = tid; idx < 32 * DH; idx += 128) {
    const int i = idx >> 7, d = idx & 127;
    float s = 0.f;
#pragma unroll
    for (int j = 0; j < 32; ++j) s += ps[i][j] * vs[j][d];
    o[(size_t)(i * SEQ + t) * HD + hd * DH + d] = f2bf(s);
  }
}

// ---- fused candidate scorer: gather KB rows, write cand_out[..,1:],
//      d = cand - pred -> swizzled LDS, t1 = relu(d @ dsW1 + b1) (MFMA),
//      cand_out[row*257] = t1 . w2 + b2. Block = 64 cand rows, 4 waves. ------
__global__ __launch_bounds__(256) void cand_score(
    const float* __restrict__ outb, const int* __restrict__ indices,
    const float* __restrict__ KB, const short* __restrict__ W1T,
    const float* __restrict__ b1v, const float* __restrict__ w2v,
    const float* __restrict__ b2v, float* __restrict__ cand_out) {
  __shared__ alignas(16) short Asw[8 * 2048];        // [kslice][64 rows][32] 32KB
  __shared__ alignas(16) short Bs0[8192], Bs1[8192]; // 16KB each
  __shared__ float red[64];
  const int tid = threadIdx.x;
  const int lane = tid & 63, wave = tid >> 6;        // 4 waves; wave = col-block
  const int lrow = lane & 15, ks = lane >> 4;
  const int sx = (lrow >> 1) & 3;
  const int koff = ((ks ^ sx) << 3);
  const int r0 = blockIdx.x << 6;

  // ---- gather + diff + swizzled A write + cand_out write (coalesced) ------
  {
    const int l4 = lane << 2;                        // col base 0..252
    const int kslice = l4 >> 5, kslot = (l4 >> 3) & 3, kin = l4 & 7;
#pragma unroll
    for (int it = 0; it < 16; ++it) {
      const int rr = wave + (it << 2);               // row 0..63 (wave-uniform)
      const int R = r0 + rr;
      const int bs = R / KC, k = R - bs * KC;
      int idx = indices[(size_t)bs * KC + k];
      if (idx < 0) idx = 0;
      const int b = bs >> 7, s = bs & 127;
      f32x4 cv = *(const f32x4*)(KB + (size_t)idx * OUT_DIM + l4);
      f32x4 pv = *(const f32x4*)(outb + ((size_t)b * SEQ + s + 1) * OUT_DIM + l4);
      float* co = cand_out + (size_t)R * 257 + 1 + l4;
      co[0] = cv.x; co[1] = cv.y; co[2] = cv.z; co[3] = cv.w;
      u16x4 dv;
      dv.x = (unsigned short)f2bf(cv.x - pv.x);
      dv.y = (unsigned short)f2bf(cv.y - pv.y);
      dv.z = (unsigned short)f2bf(cv.z - pv.z);
      dv.w = (unsigned short)f2bf(cv.w - pv.w);
      const int rsw = (rr >> 1) & 3;
      *(u16x4*)&Asw[kslice * 2048 + rr * 32 + ((kslot ^ rsw) << 3) + kin] = dv;
    }
  }
  if (tid < 64) red[tid] = 0.f;

  // ---- B staging pointers (dsW1T: 256 rows x 256 K, pre-swizzled src) ------
  const short* pb[4];
#pragma unroll
  for (int i = 0; i < 4; ++i) {
    const int idx2 = i * 256 + tid;
    const int rr = idx2 >> 2, ss = idx2 & 3, gg = ss ^ ((rr >> 1) & 3);
    pb[i] = W1T + (size_t)rr * 256 + gg * 8;
  }
  auto stageB = [&](short* buf, int t) {
#pragma unroll
    for (int i = 0; i < 4; ++i)
      gload16(pb[i] + (t << 5), buf + i * 2048 + wave * 512);
  };

  f32x4 acc[4][4] = {};
  auto computeDS = [&](const short* as, const short* bsrc) {
    s16x8 af[4], bfr[4];
#pragma unroll
    for (int m = 0; m < 4; ++m)
      af[m] = *(const s16x8*)&as[(m * 16 + lrow) * 32 + koff];
#pragma unroll
    for (int n = 0; n < 4; ++n)
      bfr[n] = *(const s16x8*)&bsrc[(wave * 64 + n * 16 + lrow) * 32 + koff];
#pragma unroll
    for (int m = 0; m < 4; ++m)
#pragma unroll
      for (int n = 0; n < 4; ++n)
        asm("v_mfma_f32_16x16x32_bf16 %0, %1, %2, %0"
            : "+v"(acc[m][n]) : "v"(af[m]), "v"(bfr[n]));
  };

  stageB(Bs0, 0);
  __syncthreads();                       // A writes + red init + Bs0 loads
  for (int t = 0; t < 8; t += 2) {
    stageB(Bs1, t + 1);
    computeDS(Asw + t * 2048, Bs0);
    __syncthreads();
    if (t + 2 < 8) stageB(Bs0, t + 2);
    computeDS(Asw + (t + 1) * 2048, Bs1);
    __syncthreads();
  }

  // ---- fused score epilogue (validated round-5 pattern) --------------------
  float w2r[4], b1r[4];
#pragma unroll
  for (int n = 0; n < 4; ++n) {
    const int col = wave * 64 + n * 16 + lrow;
    w2r[n] = w2v[col];
    b1r[n] = b1v[col];
  }
#pragma unroll
  for (int m = 0; m < 4; ++m) {
#pragma unroll
    for (int r2 = 0; r2 < 4; ++r2) {
      float part = 0.f;
#pragma unroll
      for (int n = 0; n < 4; ++n)
        part += fmaxf(acc[m][n][r2] + b1r[n], 0.f) * w2r[n];
      part += __shfl_xor(part, 1);
      part += __shfl_xor(part, 2);
      part += __shfl_xor(part, 4);
      part += __shfl_xor(part, 8);
      if (lrow == 0) atomicAdd(&red[m * 16 + ks * 4 + r2], part);
    }
  }
  __syncthreads();
  if (tid < 64)
    cand_out[(size_t)(r0 + tid) * 257] = red[tid] + b2v[0];
}

extern "C" void kernel_launch(void* const* d_in, const int* in_sizes, int n_in,
                              void* d_out, int out_size, void* d_ws, size_t ws_size,
                              hipStream_t stream) {
  const float* x      = (const float*)d_in[0];
  const float* ctx    = (const float*)d_in[1];
  const int*   indices= (const int*)d_in[2];
  const float* KB     = (const float*)d_in[3];
  const float* W_in   = (const float*)d_in[4];
  const float* b_in   = (const float*)d_in[5];
  const float* Wqkv   = (const float*)d_in[6];
  const float* bqkv   = (const float*)d_in[7];
  const float* Wo     = (const float*)d_in[8];
  const float* bo     = (const float*)d_in[9];
  const float* ln1_g  = (const float*)d_in[10];
  const float* ln1_b  = (const float*)d_in[11];
  const float* W1     = (const float*)d_in[12];
  const float* b1     = (const float*)d_in[13];
  const float* W2     = (const float*)d_in[14];
  const float* b2     = (const float*)d_in[15];
  const float* ln2_g  = (const float*)d_in[16];
  const float* ln2_b  = (const float*)d_in[17];
  const float* W_out  = (const float*)d_in[18];
  const float* b_out  = (const float*)d_in[19];
  const float* ds_W1  = (const float*)d_in[20];
  const float* ds_b1  = (const float*)d_in[21];
  const float* ds_W2  = (const float*)d_in[22];
  const float* ds_b2  = (const float*)d_in[23];
  // d_in[24..27] = cs_* : dead code in reference (del cs)

  char* p = (char*)d_ws;
  auto alloc = [&](size_t bytes) {
    char* q = p;
    p += (bytes + 255) & ~(size_t)255;
    return q;
  };
  short* h    = (short*)alloc((size_t)MPAD * HD * 2);
  short* tmp1 = (short*)alloc((size_t)MPAD * 3 * HD * 2);  // qkv / ff1
  short* tmp2 = (short*)alloc((size_t)MPAD * HD * 2);      // hin / attn-o
  float* outb = (float*)alloc((size_t)MROWS * OUT_DIM * 4);
  float* part = (float*)alloc((size_t)2 * MPAD * HD * 4);  // split-K partials
  short* WinT  = (short*)alloc((size_t)HD * IN_DIM * 2);
  short* WqkvT = (short*)alloc((size_t)2 * 3 * HD * HD * 2);
  short* WoT   = (short*)alloc((size_t)2 * HD * HD * 2);
  short* W1T   = (short*)alloc((size_t)2 * DFF * HD * 2);
  short* W2T   = (short*)alloc((size_t)2 * HD * DFF * 2);
  short* WoutT = (short*)alloc((size_t)OUT_DIM * HD * 2);
  short* dsW1T = (short*)alloc((size_t)OUT_DIM * OUT_DIM * 2);

  // all weight transposes (f32 -> bf16, N x K) in ONE dispatch
  transpose_all<<<17728, 256, 0, stream>>>(W_in, Wqkv, Wo, W1, W2, W_out, ds_W1,
                                           WinT, WqkvT, WoT, W1T, W2T, WoutT, dsW1T);

  // forward
  build_hin<<<MROWS, 256, 0, stream>>>(x, ctx, tmp2);
  // Win: split-K x2 (528 blocks), reduce+bias+relu -> h (bf16)
  gemm_bt<0, true, short><<<33 * 8 * 2, 256, 0, stream>>>(
      tmp2, WinT, nullptr, nullptr, part, MROWS, 1024, 1024, 33, 8, 8, 512);
  reduce_cast<1, short><<<MROWS, 256, 0, stream>>>(part, b_in, h, 1024, 2);

  for (int l = 0; l < 2; ++l) {
    gemm_bt<0, false, short><<<33 * 24, 256, 0, stream>>>(
        h, WqkvT + (size_t)l * 3072 * 1024, bqkv + l * 3072, tmp1, nullptr,
        MROWS, 3072, 1024, 33, 24, 8, 0);
    attention_kern<<<dim3(SEQ, NHEAD), 128, 0, stream>>>(tmp1, tmp2);
    // Wo: split-K x2, fused reduce + residual + LN -> h
    gemm_bt<0, true, short><<<33 * 8 * 2, 256, 0, stream>>>(
        tmp2, WoT + (size_t)l * 1024 * 1024, nullptr, nullptr, part,
        MROWS, 1024, 1024, 33, 8, 8, 512);
    reduce_ln<<<MROWS, 256, 0, stream>>>(part, bo + l * 1024,
                                         ln1_g + l * 1024, ln1_b + l * 1024, h);
    gemm_bt<1, false, short><<<33 * 16, 256, 0, stream>>>(
        h, W1T + (size_t)l * 2048 * 1024, b1 + l * 2048, tmp1, nullptr,
        MROWS, 2048, 1024, 33, 16, 8, 0);
    // W2: split-K x2 (K=2048 -> 1024 each), fused reduce + residual + LN -> h
    gemm_bt<0, true, short><<<33 * 8 * 2, 256, 0, stream>>>(
        tmp1, W2T + (size_t)l * 1024 * 2048, nullptr, nullptr, part,
        MROWS, 1024, 2048, 33, 8, 4, 1024);
    reduce_ln<<<MROWS, 256, 0, stream>>>(part, b2 + l * 1024,
                                         ln2_g + l * 1024, ln2_b + l * 1024, h);
  }

  float* pred = (float*)d_out;
  float* cand_out = (float*)d_out + (size_t)B_ * S_ * OUT_DIM;

  // Wout: split-K x4 (264 blocks), reduce -> outb (f32) + pred (d_out)
  gemm_bt<0, true, float><<<33 * 2 * 4, 256, 0, stream>>>(
      h, WoutT, nullptr, nullptr, part, MROWS, 256, 1024, 33, 2, 8, 256);
  reduce_wout<<<MROWS, 64, 0, stream>>>(part, b_out, outb, pred);

  // fused gather + ds-GEMM + score (640 blocks x 64 rows)
  cand_score<<<NCAND / 64, 256, 0, stream>>>(outb, indices, KB, dsW1T,
                                             ds_b1, ds_W2, ds_b2, cand_out);
}